// Round 1
// baseline (1982.489 us; speedup 1.0000x reference)
//
#include <hip/hip_runtime.h>
#include <hip/hip_bf16.h>
#include <math.h>

// Problem constants (fixed by harness)
#define T_LEN 2048
#define EMB   2048
#define NH    32
#define HD    64
#define HALF  32

// ---------------------------------------------------------------------------
// GEMM:  C[M,N] = A[M,K] * B[N,K]^T + bias[N]      (fp32, tiled)
// Both A and B are K-contiguous (row-major). 64x64 tile, BK=32, 256 threads,
// each thread computes a 4x4 micro-tile. LDS padded +1 (2-way conflicts max,
// which are free on CDNA4).
// ---------------------------------------------------------------------------
#define BM 64
#define BN 64
#define BKK 32

__global__ __launch_bounds__(256) void gemm_nt_bias(
    const float* __restrict__ A,
    const float* __restrict__ B,
    const float* __restrict__ bias,
    float* __restrict__ C,
    int M, int N, int K)
{
    __shared__ float As[BM][BKK + 1];
    __shared__ float Bs[BN][BKK + 1];
    const int bm = blockIdx.y * BM;
    const int bn = blockIdx.x * BN;
    const int tid = threadIdx.x;
    const int tx = tid & 15;   // 16 col-groups
    const int ty = tid >> 4;   // 16 row-groups
    float acc[4][4] = {};

    // loader mapping: 64 rows x 32 cols = 2048 floats = 8 per thread (2x float4)
    const int lr = tid >> 3;        // 0..31
    const int lc = (tid & 7) * 4;   // 0..28 step 4

    for (int k0 = 0; k0 < K; k0 += BKK) {
        float4 a0 = *reinterpret_cast<const float4*>(&A[(size_t)(bm + lr)      * K + k0 + lc]);
        float4 a1 = *reinterpret_cast<const float4*>(&A[(size_t)(bm + lr + 32) * K + k0 + lc]);
        float4 b0 = *reinterpret_cast<const float4*>(&B[(size_t)(bn + lr)      * K + k0 + lc]);
        float4 b1 = *reinterpret_cast<const float4*>(&B[(size_t)(bn + lr + 32) * K + k0 + lc]);
        __syncthreads();   // previous iteration's reads complete
        As[lr][lc + 0] = a0.x; As[lr][lc + 1] = a0.y; As[lr][lc + 2] = a0.z; As[lr][lc + 3] = a0.w;
        As[lr + 32][lc + 0] = a1.x; As[lr + 32][lc + 1] = a1.y; As[lr + 32][lc + 2] = a1.z; As[lr + 32][lc + 3] = a1.w;
        Bs[lr][lc + 0] = b0.x; Bs[lr][lc + 1] = b0.y; Bs[lr][lc + 2] = b0.z; Bs[lr][lc + 3] = b0.w;
        Bs[lr + 32][lc + 0] = b1.x; Bs[lr + 32][lc + 1] = b1.y; Bs[lr + 32][lc + 2] = b1.z; Bs[lr + 32][lc + 3] = b1.w;
        __syncthreads();
        #pragma unroll
        for (int kk = 0; kk < BKK; ++kk) {
            float av[4], bv[4];
            #pragma unroll
            for (int i = 0; i < 4; ++i) av[i] = As[ty * 4 + i][kk];
            #pragma unroll
            for (int j = 0; j < 4; ++j) bv[j] = Bs[tx * 4 + j][kk];
            #pragma unroll
            for (int i = 0; i < 4; ++i)
                #pragma unroll
                for (int j = 0; j < 4; ++j)
                    acc[i][j] += av[i] * bv[j];
        }
    }
    #pragma unroll
    for (int i = 0; i < 4; ++i) {
        const int row = bm + ty * 4 + i;
        #pragma unroll
        for (int j = 0; j < 4; ++j) {
            const int col = bn + tx * 4 + j;
            C[(size_t)row * N + col] = acc[i][j] + bias[col];
        }
    }
}

// ---------------------------------------------------------------------------
// Rotary (xPos, interleaved rotate-every-two) applied in-place to Q and K.
//   K: scale = 1/xscale ;  Q: scale = xscale, then * scale_attention(t) * HD^-0.5
// out[2p]   = x[2p]*C - x[2p+1]*S ;  out[2p+1] = x[2p+1]*C + x[2p]*S
// with C = cos[t,p]*scale, S = sin[t,p]*scale.
// scale_attention(t) = max(1, log(t)/log(1024))  (t=0 -> 1 since log(0)=-inf)
// ---------------------------------------------------------------------------
__global__ __launch_bounds__(256) void rotary_kernel(
    float* __restrict__ Q, float* __restrict__ Kmat,
    const float* __restrict__ sinp, const float* __restrict__ cosp,
    const float* __restrict__ xscale)
{
    const int idx = blockIdx.x * blockDim.x + threadIdx.x;  // T*NH*HALF = 2M
    if (idx >= T_LEN * NH * HALF) return;
    const int t = idx >> 10;       // / (NH*HALF)
    const int r = idx & 1023;
    const int h = r >> 5;
    const int p = r & 31;

    const float s  = sinp[t * HALF + p];
    const float c  = cosp[t * HALF + p];
    const float xs = xscale[t * HALF + p];
    const float inv_xs = 1.0f / xs;
    const size_t off = (size_t)t * EMB + h * HD + 2 * p;

    // K with scale 1/xscale
    {
        const float Ck = c * inv_xs, Sk = s * inv_xs;
        const float k0 = Kmat[off], k1 = Kmat[off + 1];
        Kmat[off]     = k0 * Ck - k1 * Sk;
        Kmat[off + 1] = k1 * Ck + k0 * Sk;
    }
    // Q with scale xscale, fold in scale_attention(t) and HD^-0.5 = 0.125
    {
        float sa = 1.0f;
        if (t >= 2) {
            const float v = logf((float)t) * (1.0f / 6.9314718055994531f); // /log(1024)
            sa = v > 1.0f ? v : 1.0f;
        }
        const float qs = sa * 0.125f;
        const float Cq = c * xs * qs, Sq = s * xs * qs;
        const float q0 = Q[off], q1 = Q[off + 1];
        Q[off]     = q0 * Cq - q1 * Sq;
        Q[off + 1] = q1 * Cq + q0 * Sq;
    }
}

// ---------------------------------------------------------------------------
// Causal flash attention, fp32, online softmax.
// Grid: (NH heads, T/64 q-blocks). Block: 256 threads.
// Thread (row = tid>>2, part = tid&3) owns 16 dims of q-row (qb*64+row).
// K/V tiles (64x64) staged in LDS; per-4-j group: partial dots, 4-lane
// shfl_xor reduce, online max/sum update, O accumulate.
// O may alias Q (block reads only its own Q rows before writing them).
// ---------------------------------------------------------------------------
__global__ __launch_bounds__(256) void flash_attn(
    const float* __restrict__ Q,
    const float* __restrict__ Kmat,
    const float* __restrict__ V,
    float* __restrict__ O)
{
    __shared__ float Ks[64][HD];
    __shared__ float Vs[64][HD];
    const int h   = blockIdx.x;
    const int qb  = blockIdx.y;
    const int tid = threadIdx.x;
    const int row = tid >> 2;       // 0..63
    const int part = tid & 3;       // 16-dim chunk
    const int t = qb * 64 + row;    // global q row
    const int colbase = h * HD;

    float q[16], o[16];
    #pragma unroll
    for (int i = 0; i < 16; ++i) {
        q[i] = Q[(size_t)t * EMB + colbase + part * 16 + i];
        o[i] = 0.f;
    }
    float m = -1e30f, l = 0.f;

    for (int kb = 0; kb <= qb; ++kb) {
        __syncthreads();   // previous tile fully consumed
        {
            const int r0 = tid >> 2;
            const int sl = tid & 3;
            const float* Kg = &Kmat[(size_t)(kb * 64 + r0) * EMB + colbase];
            const float* Vg = &V   [(size_t)(kb * 64 + r0) * EMB + colbase];
            #pragma unroll
            for (int i = 0; i < 4; ++i) {
                const int c4 = sl + i * 4;  // float4 slot 0..15
                *reinterpret_cast<float4*>(&Ks[r0][c4 * 4]) =
                    *reinterpret_cast<const float4*>(&Kg[c4 * 4]);
                *reinterpret_cast<float4*>(&Vs[r0][c4 * 4]) =
                    *reinterpret_cast<const float4*>(&Vg[c4 * 4]);
            }
        }
        __syncthreads();

        #pragma unroll 1
        for (int jg = 0; jg < 16; ++jg) {
            float s[4] = {0.f, 0.f, 0.f, 0.f};
            #pragma unroll
            for (int i4 = 0; i4 < 4; ++i4) {
                #pragma unroll
                for (int jj = 0; jj < 4; ++jj) {
                    const float4 kv = *reinterpret_cast<const float4*>(
                        &Ks[jg * 4 + jj][part * 16 + i4 * 4]);
                    s[jj] += q[i4 * 4 + 0] * kv.x + q[i4 * 4 + 1] * kv.y
                           + q[i4 * 4 + 2] * kv.z + q[i4 * 4 + 3] * kv.w;
                }
            }
            // reduce the 4 partial dots across the 4 lanes of this row
            #pragma unroll
            for (int jj = 0; jj < 4; ++jj) {
                s[jj] += __shfl_xor(s[jj], 1);
                s[jj] += __shfl_xor(s[jj], 2);
            }
            const int cbase = kb * 64 + jg * 4;
            #pragma unroll
            for (int jj = 0; jj < 4; ++jj)
                if (cbase + jj > t) s[jj] = -1e30f;

            const float smax = fmaxf(fmaxf(s[0], s[1]), fmaxf(s[2], s[3]));
            const float mnew = fmaxf(m, smax);
            const float corr = __expf(m - mnew);
            float p[4], psum = 0.f;
            #pragma unroll
            for (int jj = 0; jj < 4; ++jj) {
                p[jj] = (cbase + jj <= t) ? __expf(s[jj] - mnew) : 0.f;
                psum += p[jj];
            }
            l = l * corr + psum;
            m = mnew;
            #pragma unroll
            for (int i4 = 0; i4 < 4; ++i4) {
                float4 v0 = *reinterpret_cast<const float4*>(&Vs[jg * 4 + 0][part * 16 + i4 * 4]);
                float4 v1 = *reinterpret_cast<const float4*>(&Vs[jg * 4 + 1][part * 16 + i4 * 4]);
                float4 v2 = *reinterpret_cast<const float4*>(&Vs[jg * 4 + 2][part * 16 + i4 * 4]);
                float4 v3 = *reinterpret_cast<const float4*>(&Vs[jg * 4 + 3][part * 16 + i4 * 4]);
                #pragma unroll
                for (int ii = 0; ii < 4; ++ii) {
                    const int i = i4 * 4 + ii;
                    float acc = o[i] * corr;
                    const float vv0 = (&v0.x)[ii], vv1 = (&v1.x)[ii];
                    const float vv2 = (&v2.x)[ii], vv3 = (&v3.x)[ii];
                    acc += p[0] * vv0 + p[1] * vv1 + p[2] * vv2 + p[3] * vv3;
                    o[i] = acc;
                }
            }
        }
    }
    const float invl = 1.f / l;
    #pragma unroll
    for (int i = 0; i < 16; ++i)
        O[(size_t)t * EMB + colbase + part * 16 + i] = o[i] * invl;
}

// ---------------------------------------------------------------------------
// Launch
// inputs: 0 query, 1 key, 2 value, 3 Wq, 4 bq, 5 Wk, 6 bk, 7 Wv, 8 bv,
//         9 Wo, 10 bo, 11 sin, 12 cos, 13 xscale, 14 attn_mask, 15 scale_length
// Workspace: Q (16MB) | K (16MB) | V (16MB)  — O aliases Q (safe, see kernel).
// ---------------------------------------------------------------------------
extern "C" void kernel_launch(void* const* d_in, const int* in_sizes, int n_in,
                              void* d_out, int out_size, void* d_ws, size_t ws_size,
                              hipStream_t stream) {
    const float* query = (const float*)d_in[0];
    const float* key   = (const float*)d_in[1];
    const float* value = (const float*)d_in[2];
    const float* Wq = (const float*)d_in[3];
    const float* bq = (const float*)d_in[4];
    const float* Wk = (const float*)d_in[5];
    const float* bk = (const float*)d_in[6];
    const float* Wv = (const float*)d_in[7];
    const float* bv = (const float*)d_in[8];
    const float* Wo = (const float*)d_in[9];
    const float* bo = (const float*)d_in[10];
    const float* sinp   = (const float*)d_in[11];
    const float* cosp   = (const float*)d_in[12];
    const float* xscale = (const float*)d_in[13];
    float* out = (float*)d_out;

    const size_t MAT = (size_t)T_LEN * EMB;   // 4M floats
    float* q_ws = (float*)d_ws;
    float* k_ws = q_ws + MAT;
    float* v_ws = k_ws + MAT;
    float* o_ws = q_ws;                       // alias: flash_attn writes O over Q

    dim3 gGemm(EMB / BN, T_LEN / BM);
    gemm_nt_bias<<<gGemm, 256, 0, stream>>>(query, Wq, bq, q_ws, T_LEN, EMB, EMB);
    gemm_nt_bias<<<gGemm, 256, 0, stream>>>(key,   Wk, bk, k_ws, T_LEN, EMB, EMB);
    gemm_nt_bias<<<gGemm, 256, 0, stream>>>(value, Wv, bv, v_ws, T_LEN, EMB, EMB);

    const int nrot = T_LEN * NH * HALF;
    rotary_kernel<<<nrot / 256, 256, 0, stream>>>(q_ws, k_ws, sinp, cosp, xscale);

    dim3 gFlash(NH, T_LEN / 64);
    flash_attn<<<gFlash, 256, 0, stream>>>(q_ws, k_ws, v_ws, o_ws);

    gemm_nt_bias<<<gGemm, 256, 0, stream>>>(o_ws, Wo, bo, out, T_LEN, EMB, EMB);
}

// Round 2
// 841.042 us; speedup vs baseline: 2.3572x; 2.3572x over previous
//
#include <hip/hip_runtime.h>
#include <hip/hip_bf16.h>
#include <math.h>

// Problem constants (fixed by harness)
#define T_LEN 2048
#define EMB   2048
#define NH    32
#define HD    64
#define HALF  32

typedef __attribute__((ext_vector_type(8))) short short8v;   // 8 bf16 (4 VGPR)
typedef __attribute__((ext_vector_type(4))) float floatx4;   // MFMA C/D

// async global->LDS, 16B per lane. LDS dest must be wave-uniform base;
// HW writes lane l's data at base + l*16. Global src is per-lane.
__device__ inline void gload_lds16(const void* g, void* l) {
    __builtin_amdgcn_global_load_lds(
        (const __attribute__((address_space(1))) unsigned int*)g,
        (__attribute__((address_space(3))) unsigned int*)l,
        16, 0, 0);
}

__device__ inline ushort f2bf(float x) {
    union { float f; unsigned u; } c; c.f = x;
    const unsigned r = c.u + 0x7FFFu + ((c.u >> 16) & 1u);  // RNE
    return (ushort)(r >> 16);
}

// ---------------------------------------------------------------------------
// fp32 -> bf16 conversion, 8 elem/thread, vectorized
// ---------------------------------------------------------------------------
__global__ __launch_bounds__(256) void f32_to_bf16_k(
    const float* __restrict__ in, ushort* __restrict__ out, int n)
{
    const int i = (blockIdx.x * 256 + threadIdx.x) * 8;
    if (i >= n) return;
    const float4 v0 = *reinterpret_cast<const float4*>(&in[i]);
    const float4 v1 = *reinterpret_cast<const float4*>(&in[i + 4]);
    ushort o[8];
    o[0] = f2bf(v0.x); o[1] = f2bf(v0.y); o[2] = f2bf(v0.z); o[3] = f2bf(v0.w);
    o[4] = f2bf(v1.x); o[5] = f2bf(v1.y); o[6] = f2bf(v1.z); o[7] = f2bf(v1.w);
    *reinterpret_cast<uint4*>(&out[i]) = *reinterpret_cast<const uint4*>(o);
}

// ---------------------------------------------------------------------------
// bf16 MFMA GEMM (m97 structure):  C[M,N] = A[M,K] * B[N,K]^T + bias[N]
// 128x128 tile, BK=64, 256 threads = 4 waves (2x2), each wave a 64x64
// sub-tile as 4x4 fragments of 16x16x32 MFMA. global_load_lds(16B) staging,
// linear LDS (no swizzle: T2 is null at 2-phase structures), fp32 accum.
// C/D layout: col = lane&15, row = (lane>>4)*4 + reg  [m89/m91 verified].
// A/B frag:   lane holds X[row=lane&15][k = (lane>>4)*8 .. +7].
// ---------------------------------------------------------------------------
#define GBM 128
#define GBN 128
#define GBK 64

__global__ __launch_bounds__(256) void gemm_bf16_nt(
    const ushort* __restrict__ A,   // [M][K] bf16
    const ushort* __restrict__ B,   // [N][K] bf16
    const float* __restrict__ bias,
    float* __restrict__ C,
    int M, int N, int K)
{
    __shared__ ushort As[GBM * GBK];   // 16 KB, row-major [128][64]
    __shared__ ushort Bs[GBN * GBK];   // 16 KB
    const int tid  = threadIdx.x;
    const int lane = tid & 63;
    const int wid  = tid >> 6;
    const int bm = blockIdx.y * GBM;
    const int bn = blockIdx.x * GBN;
    const int wr = (wid >> 1) * 64;    // wave row offset in tile
    const int wc = (wid & 1) * 64;     // wave col offset in tile

    floatx4 acc[4][4] = {};

    const int lrow  = lane >> 3;        // 0..7 row within 8-row chunk
    const int lcolb = (lane & 7) * 8;   // element offset 0..56 within BK

    for (int k0 = 0; k0 < K; k0 += GBK) {
        // stage: 16 chunks of 1024B per tile; wave w stages chunks 4w..4w+3
        #pragma unroll
        for (int c = 0; c < 4; ++c) {
            const int chunk = wid * 4 + c;          // 0..15
            const int row = chunk * 8 + lrow;       // 0..127
            gload_lds16(&A[(size_t)(bm + row) * K + k0 + lcolb], &As[chunk * 512]);
            gload_lds16(&B[(size_t)(bn + row) * K + k0 + lcolb], &Bs[chunk * 512]);
        }
        __syncthreads();   // compiler emits vmcnt(0) drain before s_barrier
        #pragma unroll
        for (int kk = 0; kk < 2; ++kk) {
            short8v a[4], b[4];
            #pragma unroll
            for (int m = 0; m < 4; ++m)
                a[m] = *reinterpret_cast<const short8v*>(
                    &As[(wr + m * 16 + (lane & 15)) * GBK + kk * 32 + (lane >> 4) * 8]);
            #pragma unroll
            for (int n = 0; n < 4; ++n)
                b[n] = *reinterpret_cast<const short8v*>(
                    &Bs[(wc + n * 16 + (lane & 15)) * GBK + kk * 32 + (lane >> 4) * 8]);
            #pragma unroll
            for (int m = 0; m < 4; ++m)
                #pragma unroll
                for (int n = 0; n < 4; ++n)
                    acc[m][n] = __builtin_amdgcn_mfma_f32_16x16x32_bf16(
                        a[m], b[n], acc[m][n], 0, 0, 0);
        }
        __syncthreads();   // all reads done before next stage overwrites
    }

    const int cr = (lane >> 4) * 4;
    const int cc = lane & 15;
    #pragma unroll
    for (int m = 0; m < 4; ++m) {
        #pragma unroll
        for (int n = 0; n < 4; ++n) {
            const int col = bn + wc + n * 16 + cc;
            const float bz = bias[col];
            #pragma unroll
            for (int j = 0; j < 4; ++j) {
                const int row = bm + wr + m * 16 + cr + j;
                C[(size_t)row * N + col] = acc[m][n][j] + bz;
            }
        }
    }
}

// ---------------------------------------------------------------------------
// Rotary (xPos, interleaved rotate-every-two) applied in-place to Q and K.
//   K: scale = 1/xscale ;  Q: scale = xscale * scale_attention(t) * HD^-0.5
// ---------------------------------------------------------------------------
__global__ __launch_bounds__(256) void rotary_kernel(
    float* __restrict__ Q, float* __restrict__ Kmat,
    const float* __restrict__ sinp, const float* __restrict__ cosp,
    const float* __restrict__ xscale)
{
    const int idx = blockIdx.x * blockDim.x + threadIdx.x;  // T*NH*HALF = 2M
    if (idx >= T_LEN * NH * HALF) return;
    const int t = idx >> 10;       // / (NH*HALF)
    const int r = idx & 1023;
    const int h = r >> 5;
    const int p = r & 31;

    const float s  = sinp[t * HALF + p];
    const float c  = cosp[t * HALF + p];
    const float xs = xscale[t * HALF + p];
    const float inv_xs = 1.0f / xs;
    const size_t off = (size_t)t * EMB + h * HD + 2 * p;

    {
        const float Ck = c * inv_xs, Sk = s * inv_xs;
        const float k0 = Kmat[off], k1 = Kmat[off + 1];
        Kmat[off]     = k0 * Ck - k1 * Sk;
        Kmat[off + 1] = k1 * Ck + k0 * Sk;
    }
    {
        float sa = 1.0f;
        if (t >= 2) {
            const float v = logf((float)t) * (1.0f / 6.9314718055994531f); // /log(1024)
            sa = v > 1.0f ? v : 1.0f;
        }
        const float qs = sa * 0.125f;   // * HD^-0.5
        const float Cq = c * xs * qs, Sq = s * xs * qs;
        const float q0 = Q[off], q1 = Q[off + 1];
        Q[off]     = q0 * Cq - q1 * Sq;
        Q[off + 1] = q1 * Cq + q0 * Sq;
    }
}

// ---------------------------------------------------------------------------
// Causal flash attention, fp32, online softmax (unchanged from round 1).
// O may alias Q (block reads only its own Q rows before writing them).
// ---------------------------------------------------------------------------
__global__ __launch_bounds__(256) void flash_attn(
    const float* __restrict__ Q,
    const float* __restrict__ Kmat,
    const float* __restrict__ V,
    float* __restrict__ O)
{
    __shared__ float Ks[64][HD];
    __shared__ float Vs[64][HD];
    const int h   = blockIdx.x;
    const int qb  = blockIdx.y;
    const int tid = threadIdx.x;
    const int row = tid >> 2;
    const int part = tid & 3;
    const int t = qb * 64 + row;
    const int colbase = h * HD;

    float q[16], o[16];
    #pragma unroll
    for (int i = 0; i < 16; ++i) {
        q[i] = Q[(size_t)t * EMB + colbase + part * 16 + i];
        o[i] = 0.f;
    }
    float m = -1e30f, l = 0.f;

    for (int kb = 0; kb <= qb; ++kb) {
        __syncthreads();
        {
            const int r0 = tid >> 2;
            const int sl = tid & 3;
            const float* Kg = &Kmat[(size_t)(kb * 64 + r0) * EMB + colbase];
            const float* Vg = &V   [(size_t)(kb * 64 + r0) * EMB + colbase];
            #pragma unroll
            for (int i = 0; i < 4; ++i) {
                const int c4 = sl + i * 4;
                *reinterpret_cast<float4*>(&Ks[r0][c4 * 4]) =
                    *reinterpret_cast<const float4*>(&Kg[c4 * 4]);
                *reinterpret_cast<float4*>(&Vs[r0][c4 * 4]) =
                    *reinterpret_cast<const float4*>(&Vg[c4 * 4]);
            }
        }
        __syncthreads();

        #pragma unroll 1
        for (int jg = 0; jg < 16; ++jg) {
            float s[4] = {0.f, 0.f, 0.f, 0.f};
            #pragma unroll
            for (int i4 = 0; i4 < 4; ++i4) {
                #pragma unroll
                for (int jj = 0; jj < 4; ++jj) {
                    const float4 kv = *reinterpret_cast<const float4*>(
                        &Ks[jg * 4 + jj][part * 16 + i4 * 4]);
                    s[jj] += q[i4 * 4 + 0] * kv.x + q[i4 * 4 + 1] * kv.y
                           + q[i4 * 4 + 2] * kv.z + q[i4 * 4 + 3] * kv.w;
                }
            }
            #pragma unroll
            for (int jj = 0; jj < 4; ++jj) {
                s[jj] += __shfl_xor(s[jj], 1);
                s[jj] += __shfl_xor(s[jj], 2);
            }
            const int cbase = kb * 64 + jg * 4;
            #pragma unroll
            for (int jj = 0; jj < 4; ++jj)
                if (cbase + jj > t) s[jj] = -1e30f;

            const float smax = fmaxf(fmaxf(s[0], s[1]), fmaxf(s[2], s[3]));
            const float mnew = fmaxf(m, smax);
            const float corr = __expf(m - mnew);
            float p[4], psum = 0.f;
            #pragma unroll
            for (int jj = 0; jj < 4; ++jj) {
                p[jj] = (cbase + jj <= t) ? __expf(s[jj] - mnew) : 0.f;
                psum += p[jj];
            }
            l = l * corr + psum;
            m = mnew;
            #pragma unroll
            for (int i4 = 0; i4 < 4; ++i4) {
                float4 v0 = *reinterpret_cast<const float4*>(&Vs[jg * 4 + 0][part * 16 + i4 * 4]);
                float4 v1 = *reinterpret_cast<const float4*>(&Vs[jg * 4 + 1][part * 16 + i4 * 4]);
                float4 v2 = *reinterpret_cast<const float4*>(&Vs[jg * 4 + 2][part * 16 + i4 * 4]);
                float4 v3 = *reinterpret_cast<const float4*>(&Vs[jg * 4 + 3][part * 16 + i4 * 4]);
                #pragma unroll
                for (int ii = 0; ii < 4; ++ii) {
                    const int i = i4 * 4 + ii;
                    float acc = o[i] * corr;
                    const float vv0 = (&v0.x)[ii], vv1 = (&v1.x)[ii];
                    const float vv2 = (&v2.x)[ii], vv3 = (&v3.x)[ii];
                    acc += p[0] * vv0 + p[1] * vv1 + p[2] * vv2 + p[3] * vv3;
                    o[i] = acc;
                }
            }
        }
    }
    const float invl = 1.f / l;
    #pragma unroll
    for (int i = 0; i < 16; ++i)
        O[(size_t)t * EMB + colbase + part * 16 + i] = o[i] * invl;
}

// ---------------------------------------------------------------------------
// Launch.
// Workspace (104 MB):
//   [0,16)   q_ws fp32      [16,32) k_ws fp32    [32,48) v_ws fp32
//   [48,56)  Wq bf16        [56,64) Wk bf16      [64,72) Wv bf16   [72,80) Wo bf16
//   [80,88)  Aq bf16 (reused for Ao)  [88,96) Ak bf16  [96,104) Av bf16
// O of flash aliases q_ws (safe per-block; regenerated every call).
// ---------------------------------------------------------------------------
extern "C" void kernel_launch(void* const* d_in, const int* in_sizes, int n_in,
                              void* d_out, int out_size, void* d_ws, size_t ws_size,
                              hipStream_t stream) {
    const float* query = (const float*)d_in[0];
    const float* key   = (const float*)d_in[1];
    const float* value = (const float*)d_in[2];
    const float* Wq = (const float*)d_in[3];
    const float* bq = (const float*)d_in[4];
    const float* Wk = (const float*)d_in[5];
    const float* bk = (const float*)d_in[6];
    const float* Wv = (const float*)d_in[7];
    const float* bv = (const float*)d_in[8];
    const float* Wo = (const float*)d_in[9];
    const float* bo = (const float*)d_in[10];
    const float* sinp   = (const float*)d_in[11];
    const float* cosp   = (const float*)d_in[12];
    const float* xscale = (const float*)d_in[13];
    float* out = (float*)d_out;

    const size_t MAT = (size_t)T_LEN * EMB;   // 4M elements
    char* ws = (char*)d_ws;
    float* q_ws = (float*)(ws);
    float* k_ws = (float*)(ws + 16 * 1024 * 1024);
    float* v_ws = (float*)(ws + 32 * 1024 * 1024);
    ushort* bWq = (ushort*)(ws + 48 * 1024 * 1024);
    ushort* bWk = (ushort*)(ws + 56 * 1024 * 1024);
    ushort* bWv = (ushort*)(ws + 64 * 1024 * 1024);
    ushort* bWo = (ushort*)(ws + 72 * 1024 * 1024);
    ushort* bAq = (ushort*)(ws + 80 * 1024 * 1024);
    ushort* bAk = (ushort*)(ws + 88 * 1024 * 1024);
    ushort* bAv = (ushort*)(ws + 96 * 1024 * 1024);
    ushort* bAo = bAq;                        // reuse
    float*  o_ws = q_ws;                      // flash O aliases Q

    const int ncv = (int)MAT;                 // 4M elems per tensor
    const int cvb = ncv / (256 * 8);          // 2048 blocks
    f32_to_bf16_k<<<cvb, 256, 0, stream>>>(Wq, bWq, ncv);
    f32_to_bf16_k<<<cvb, 256, 0, stream>>>(Wk, bWk, ncv);
    f32_to_bf16_k<<<cvb, 256, 0, stream>>>(Wv, bWv, ncv);
    f32_to_bf16_k<<<cvb, 256, 0, stream>>>(Wo, bWo, ncv);
    f32_to_bf16_k<<<cvb, 256, 0, stream>>>(query, bAq, ncv);
    f32_to_bf16_k<<<cvb, 256, 0, stream>>>(key,   bAk, ncv);
    f32_to_bf16_k<<<cvb, 256, 0, stream>>>(value, bAv, ncv);

    dim3 gGemm(EMB / GBN, T_LEN / GBM);       // 16 x 16
    gemm_bf16_nt<<<gGemm, 256, 0, stream>>>(bAq, bWq, bq, q_ws, T_LEN, EMB, EMB);
    gemm_bf16_nt<<<gGemm, 256, 0, stream>>>(bAk, bWk, bk, k_ws, T_LEN, EMB, EMB);
    gemm_bf16_nt<<<gGemm, 256, 0, stream>>>(bAv, bWv, bv, v_ws, T_LEN, EMB, EMB);

    const int nrot = T_LEN * NH * HALF;
    rotary_kernel<<<nrot / 256, 256, 0, stream>>>(q_ws, k_ws, sinp, cosp, xscale);

    dim3 gFlash(NH, T_LEN / 64);
    flash_attn<<<gFlash, 256, 0, stream>>>(q_ws, k_ws, v_ws, o_ws);

    f32_to_bf16_k<<<cvb, 256, 0, stream>>>(o_ws, bAo, ncv);
    gemm_bf16_nt<<<gGemm, 256, 0, stream>>>(bAo, bWo, bo, out, T_LEN, EMB, EMB);
}

// Round 3
// 299.627 us; speedup vs baseline: 6.6165x; 2.8070x over previous
//
#include <hip/hip_runtime.h>
#include <hip/hip_bf16.h>
#include <math.h>

// Problem constants (fixed by harness)
#define T_LEN 2048
#define EMB   2048
#define NH    32
#define HD    64
#define HALF  32

typedef __attribute__((ext_vector_type(8))) short short8v;   // 8 bf16 (4 VGPR)
typedef __attribute__((ext_vector_type(4))) float floatx4;   // MFMA C/D

// async global->LDS, 16B per lane. LDS dest is wave-uniform base + lane*16.
__device__ inline void gload_lds16(const void* g, void* l) {
    __builtin_amdgcn_global_load_lds(
        (const __attribute__((address_space(1))) unsigned int*)g,
        (__attribute__((address_space(3))) unsigned int*)l,
        16, 0, 0);
}

__device__ inline ushort f2bf(float x) {
    union { float f; unsigned u; } c; c.f = x;
    const unsigned r = c.u + 0x7FFFu + ((c.u >> 16) & 1u);  // RNE
    return (ushort)(r >> 16);
}

// ---------------------------------------------------------------------------
// fp32 -> bf16 conversion, 8 elem/thread, vectorized
// ---------------------------------------------------------------------------
__global__ __launch_bounds__(256) void f32_to_bf16_k(
    const float* __restrict__ in, ushort* __restrict__ out, int n)
{
    const int i = (blockIdx.x * 256 + threadIdx.x) * 8;
    if (i >= n) return;
    const float4 v0 = *reinterpret_cast<const float4*>(&in[i]);
    const float4 v1 = *reinterpret_cast<const float4*>(&in[i + 4]);
    ushort o[8];
    o[0] = f2bf(v0.x); o[1] = f2bf(v0.y); o[2] = f2bf(v0.z); o[3] = f2bf(v0.w);
    o[4] = f2bf(v1.x); o[5] = f2bf(v1.y); o[6] = f2bf(v1.z); o[7] = f2bf(v1.w);
    *reinterpret_cast<uint4*>(&out[i]) = *reinterpret_cast<const uint4*>(o);
}

// ---------------------------------------------------------------------------
// Transpose + convert: out[e][t] = bf16(in[t][e])   (2048x2048, 64x64 tiles)
// ---------------------------------------------------------------------------
__global__ __launch_bounds__(256) void transpose_f32_bf16(
    const float* __restrict__ in, ushort* __restrict__ out)
{
    __shared__ float tile[64][65];
    const int bi = blockIdx.x;   // t tile
    const int bj = blockIdx.y;   // e tile
    const int tid = threadIdx.x;
    #pragma unroll
    for (int i = 0; i < 4; ++i) {
        const int r = i * 16 + (tid >> 4);
        const float4 v = *reinterpret_cast<const float4*>(
            &in[(size_t)(bi * 64 + r) * EMB + bj * 64 + (tid & 15) * 4]);
        tile[r][(tid & 15) * 4 + 0] = v.x;
        tile[r][(tid & 15) * 4 + 1] = v.y;
        tile[r][(tid & 15) * 4 + 2] = v.z;
        tile[r][(tid & 15) * 4 + 3] = v.w;
    }
    __syncthreads();
    #pragma unroll
    for (int i = 0; i < 2; ++i) {
        const int e_ = i * 32 + (tid >> 3);
        const int t8 = (tid & 7) * 8;
        ushort o[8];
        #pragma unroll
        for (int j = 0; j < 8; ++j)
            o[j] = f2bf(tile[t8 + j][e_]);
        *reinterpret_cast<uint4*>(&out[(size_t)(bj * 64 + e_) * T_LEN + bi * 64 + t8]) =
            *reinterpret_cast<const uint4*>(o);
    }
}

// ---------------------------------------------------------------------------
// bf16 MFMA GEMM (m97 structure):  C[M,N] = A[M,K] * B[N,K]^T + bias[N]
// (unchanged from round 2 — verified)
// ---------------------------------------------------------------------------
#define GBM 128
#define GBN 128
#define GBK 64

__global__ __launch_bounds__(256) void gemm_bf16_nt(
    const ushort* __restrict__ A,   // [M][K] bf16
    const ushort* __restrict__ B,   // [N][K] bf16
    const float* __restrict__ bias,
    float* __restrict__ C,
    int M, int N, int K)
{
    __shared__ ushort As[GBM * GBK];
    __shared__ ushort Bs[GBN * GBK];
    const int tid  = threadIdx.x;
    const int lane = tid & 63;
    const int wid  = tid >> 6;
    const int bm = blockIdx.y * GBM;
    const int bn = blockIdx.x * GBN;
    const int wr = (wid >> 1) * 64;
    const int wc = (wid & 1) * 64;

    floatx4 acc[4][4] = {};

    const int lrow  = lane >> 3;
    const int lcolb = (lane & 7) * 8;

    for (int k0 = 0; k0 < K; k0 += GBK) {
        #pragma unroll
        for (int c = 0; c < 4; ++c) {
            const int chunk = wid * 4 + c;
            const int row = chunk * 8 + lrow;
            gload_lds16(&A[(size_t)(bm + row) * K + k0 + lcolb], &As[chunk * 512]);
            gload_lds16(&B[(size_t)(bn + row) * K + k0 + lcolb], &Bs[chunk * 512]);
        }
        __syncthreads();
        #pragma unroll
        for (int kk = 0; kk < 2; ++kk) {
            short8v a[4], b[4];
            #pragma unroll
            for (int m = 0; m < 4; ++m)
                a[m] = *reinterpret_cast<const short8v*>(
                    &As[(wr + m * 16 + (lane & 15)) * GBK + kk * 32 + (lane >> 4) * 8]);
            #pragma unroll
            for (int n = 0; n < 4; ++n)
                b[n] = *reinterpret_cast<const short8v*>(
                    &Bs[(wc + n * 16 + (lane & 15)) * GBK + kk * 32 + (lane >> 4) * 8]);
            #pragma unroll
            for (int m = 0; m < 4; ++m)
                #pragma unroll
                for (int n = 0; n < 4; ++n)
                    acc[m][n] = __builtin_amdgcn_mfma_f32_16x16x32_bf16(
                        a[m], b[n], acc[m][n], 0, 0, 0);
        }
        __syncthreads();
    }

    const int cr = (lane >> 4) * 4;
    const int cc = lane & 15;
    #pragma unroll
    for (int m = 0; m < 4; ++m) {
        #pragma unroll
        for (int n = 0; n < 4; ++n) {
            const int col = bn + wc + n * 16 + cc;
            const float bz = bias[col];
            #pragma unroll
            for (int j = 0; j < 4; ++j) {
                const int row = bm + wr + m * 16 + cr + j;
                C[(size_t)row * N + col] = acc[m][n][j] + bz;
            }
        }
    }
}

// ---------------------------------------------------------------------------
// Rotary (xPos) in-place on fp32 Q,K. Q also gets scale_attention * HD^-0.5.
// ---------------------------------------------------------------------------
__global__ __launch_bounds__(256) void rotary_kernel(
    float* __restrict__ Q, float* __restrict__ Kmat,
    const float* __restrict__ sinp, const float* __restrict__ cosp,
    const float* __restrict__ xscale)
{
    const int idx = blockIdx.x * blockDim.x + threadIdx.x;
    if (idx >= T_LEN * NH * HALF) return;
    const int t = idx >> 10;
    const int r = idx & 1023;
    const int h = r >> 5;
    const int p = r & 31;

    const float s  = sinp[t * HALF + p];
    const float c  = cosp[t * HALF + p];
    const float xs = xscale[t * HALF + p];
    const float inv_xs = 1.0f / xs;
    const size_t off = (size_t)t * EMB + h * HD + 2 * p;

    {
        const float Ck = c * inv_xs, Sk = s * inv_xs;
        const float k0 = Kmat[off], k1 = Kmat[off + 1];
        Kmat[off]     = k0 * Ck - k1 * Sk;
        Kmat[off + 1] = k1 * Ck + k0 * Sk;
    }
    {
        float sa = 1.0f;
        if (t >= 2) {
            const float v = logf((float)t) * (1.0f / 6.9314718055994531f);
            sa = v > 1.0f ? v : 1.0f;
        }
        const float qs = sa * 0.125f;
        const float Cq = c * xs * qs, Sq = s * xs * qs;
        const float q0 = Q[off], q1 = Q[off + 1];
        Q[off]     = q0 * Cq - q1 * Sq;
        Q[off + 1] = q1 * Cq + q0 * Sq;
    }
}

// ---------------------------------------------------------------------------
// MFMA flash attention (bf16, causal, online softmax).
// Grid: (NH, T/64). Block: 256 = 4 waves; wave w owns q rows qb*64+w*16..+15.
// Swapped QK^T: S^T = mfma(K_frag, Q_frag) -> lane holds S[q=lane&15][s=4g+r]
//   -> softmax per q-row is lane-local + shfl_xor(16/32).
// P staged per-wave in LDS [16 q][64 s] bf16 with byte^=(q&7)<<4 XOR swizzle.
// K tile [64 s][64 hd], Vt tile [64 d][64 s] staged via global_load_lds with
// PRE-SWIZZLED global source (LDS dest linear) + swizzled reads (rule #21).
// O accumulated fp32 in regs (layout q=4g+r, d=lane&15), stored bf16.
// ---------------------------------------------------------------------------
__global__ __launch_bounds__(256) void flash_attn_mfma(
    const ushort* __restrict__ Qb,   // [T][EMB] bf16 (rotary+scaled)
    const ushort* __restrict__ Kb,   // [T][EMB] bf16 (rotary)
    const ushort* __restrict__ Vt,   // [EMB][T] bf16 (per-head [d][t])
    ushort* __restrict__ Ob)         // [T][EMB] bf16
{
    __shared__ ushort Ks[64 * 64];       // 8 KB
    __shared__ ushort Vs[64 * 64];       // 8 KB
    __shared__ ushort Ps[4][16 * 64];    // 8 KB (2 KB per wave)

    const int h   = blockIdx.x;
    const int qb  = blockIdx.y;
    const int tid = threadIdx.x;
    const int lane = tid & 63;
    const int wid  = tid >> 6;
    const int qrow_w = qb * 64 + wid * 16;
    const int lm = lane & 15;      // fragment row index
    const int lg = lane >> 4;      // k-group 0..3

    // Q fragments (b-operand): lane holds Q[q=lm][k-chunk kk*32 + lg*8 .. +7]
    short8v qf[2];
    {
        const ushort* qp = &Qb[(size_t)(qrow_w + lm) * EMB + h * HD + lg * 8];
        qf[0] = *reinterpret_cast<const short8v*>(qp);
        qf[1] = *reinterpret_cast<const short8v*>(qp + 32);
    }

    floatx4 oacc[4] = {};            // O[q=4*lg+r][d tile td], col lm = d
    float m = -1e30f, l = 0.f;

    const int srow = lane >> 3;      // staging: row within 8-row slot
    const int schk = lane & 7;       // staging: 16B chunk within 128B row

    for (int kb = 0; kb <= qb; ++kb) {
        __syncthreads();             // previous tile fully consumed
        #pragma unroll
        for (int i = 0; i < 2; ++i) {
            const int slot = wid * 2 + i;         // 0..7
            const int row  = slot * 8 + srow;     // 0..63
            const int cswz = (schk ^ (row & 7)) * 8;   // pre-swizzled elem offset
            gload_lds16(&Kb[(size_t)(kb * 64 + row) * EMB + h * HD + cswz],
                        &Ks[slot * 512]);
            gload_lds16(&Vt[(size_t)(h * HD + row) * T_LEN + kb * 64 + cswz],
                        &Vs[slot * 512]);
        }
        __syncthreads();             // vmcnt drained by compiler before barrier

        // ---- QK^T (swapped): 4 s-tiles x 2 k-chunks
        float sv[16];
        #pragma unroll
        for (int t = 0; t < 4; ++t) {
            floatx4 sacc = {};
            const int srow_l = t * 16 + lm;       // s within tile-block
            const char* krow = reinterpret_cast<const char*>(Ks) + srow_l * 128;
            const int swz = (srow_l & 7) << 4;
            #pragma unroll
            for (int kk = 0; kk < 2; ++kk) {
                const int cb = (kk * 64 + lg * 16) ^ swz;
                short8v kf = *reinterpret_cast<const short8v*>(krow + cb);
                sacc = __builtin_amdgcn_mfma_f32_16x16x32_bf16(kf, qf[kk], sacc, 0, 0, 0);
            }
            sv[t * 4 + 0] = sacc[0]; sv[t * 4 + 1] = sacc[1];
            sv[t * 4 + 2] = sacc[2]; sv[t * 4 + 3] = sacc[3];
        }

        // causal mask: only the diagonal block needs it
        const int qg = qrow_w + lm;
        if (kb == qb) {
            #pragma unroll
            for (int t = 0; t < 4; ++t)
                #pragma unroll
                for (int r = 0; r < 4; ++r) {
                    const int sg = kb * 64 + t * 16 + lg * 4 + r;
                    if (sg > qg) sv[t * 4 + r] = -1e30f;
                }
        }

        // ---- online softmax (per q-row = lm, values lane-local)
        float mx = sv[0];
        #pragma unroll
        for (int i = 1; i < 16; ++i) mx = fmaxf(mx, sv[i]);
        mx = fmaxf(mx, __shfl_xor(mx, 16));
        mx = fmaxf(mx, __shfl_xor(mx, 32));
        const float mnew = fmaxf(m, mx);
        const float corr = __expf(m - mnew);
        m = mnew;
        float ps = 0.f;
        ushort pb[16];
        #pragma unroll
        for (int i = 0; i < 16; ++i) {
            const float p = __expf(sv[i] - mnew);
            ps += p;
            pb[i] = f2bf(p);
        }
        ps += __shfl_xor(ps, 16);
        ps += __shfl_xor(ps, 32);
        l = l * corr + ps;

        // ---- write P to per-wave LDS [q=lm][s], swizzled (8B per s-tile)
        {
            char* pbase = reinterpret_cast<char*>(&Ps[wid][0]) + lm * 128;
            const int swz = (lm & 7) << 4;
            #pragma unroll
            for (int t = 0; t < 4; ++t) {
                uint2 w;
                w.x = (unsigned)pb[t * 4 + 0] | ((unsigned)pb[t * 4 + 1] << 16);
                w.y = (unsigned)pb[t * 4 + 2] | ((unsigned)pb[t * 4 + 3] << 16);
                const int cb = (t * 32 + lg * 8) ^ swz;
                *reinterpret_cast<uint2*>(pbase + cb) = w;
            }
        }

        // ---- rescale O by corr (per O-row q = 4*lg + r)
        float corr4[4];
        #pragma unroll
        for (int r = 0; r < 4; ++r)
            corr4[r] = __shfl(corr, lg * 4 + r);
        #pragma unroll
        for (int td = 0; td < 4; ++td)
            #pragma unroll
            for (int r = 0; r < 4; ++r)
                oacc[td][r] *= corr4[r];

        // ---- PV: a = P rows (q), b = Vt rows (d); k = s (2 chunks)
        const char* pwave = reinterpret_cast<const char*>(&Ps[wid][0]);
        #pragma unroll
        for (int kk = 0; kk < 2; ++kk) {
            const int acb = (kk * 64 + lg * 16) ^ ((lm & 7) << 4);
            short8v pa = *reinterpret_cast<const short8v*>(pwave + lm * 128 + acb);
            #pragma unroll
            for (int td = 0; td < 4; ++td) {
                const int d = td * 16 + lm;
                const int bcb = (kk * 64 + lg * 16) ^ ((d & 7) << 4);
                short8v vb = *reinterpret_cast<const short8v*>(
                    reinterpret_cast<const char*>(Vs) + d * 128 + bcb);
                oacc[td] = __builtin_amdgcn_mfma_f32_16x16x32_bf16(pa, vb, oacc[td], 0, 0, 0);
            }
        }
    }

    // ---- epilogue: normalize by l, store bf16
    float invl[4];
    #pragma unroll
    for (int r = 0; r < 4; ++r)
        invl[r] = 1.f / __shfl(l, lg * 4 + r);
    #pragma unroll
    for (int td = 0; td < 4; ++td) {
        #pragma unroll
        for (int r = 0; r < 4; ++r) {
            const int trow = qrow_w + lg * 4 + r;
            const int col  = h * HD + td * 16 + lm;
            Ob[(size_t)trow * EMB + col] = f2bf(oacc[td][r] * invl[r]);
        }
    }
}

// ---------------------------------------------------------------------------
// Launch. Workspace (104 MB), with region reuse:
//   +0   q_ws fp32   +16M k_ws fp32   +32M v_ws fp32
//   +48M bWq  -> reused as bVt after QKV GEMMs
//   +56M bWk        +64M bWv         +72M bWo (live till end)
//   +80M bAq -> bQ   +88M bAk -> bAo  +96M bAv -> bK
// ---------------------------------------------------------------------------
extern "C" void kernel_launch(void* const* d_in, const int* in_sizes, int n_in,
                              void* d_out, int out_size, void* d_ws, size_t ws_size,
                              hipStream_t stream) {
    const float* query = (const float*)d_in[0];
    const float* key   = (const float*)d_in[1];
    const float* value = (const float*)d_in[2];
    const float* Wq = (const float*)d_in[3];
    const float* bq = (const float*)d_in[4];
    const float* Wk = (const float*)d_in[5];
    const float* bk = (const float*)d_in[6];
    const float* Wv = (const float*)d_in[7];
    const float* bv = (const float*)d_in[8];
    const float* Wo = (const float*)d_in[9];
    const float* bo = (const float*)d_in[10];
    const float* sinp   = (const float*)d_in[11];
    const float* cosp   = (const float*)d_in[12];
    const float* xscale = (const float*)d_in[13];
    float* out = (float*)d_out;

    const size_t MB = 1024 * 1024;
    char* ws = (char*)d_ws;
    float* q_ws = (float*)(ws);
    float* k_ws = (float*)(ws + 16 * MB);
    float* v_ws = (float*)(ws + 32 * MB);
    ushort* bWq = (ushort*)(ws + 48 * MB);
    ushort* bWk = (ushort*)(ws + 56 * MB);
    ushort* bWv = (ushort*)(ws + 64 * MB);
    ushort* bWo = (ushort*)(ws + 72 * MB);
    ushort* bAq = (ushort*)(ws + 80 * MB);
    ushort* bAk = (ushort*)(ws + 88 * MB);
    ushort* bAv = (ushort*)(ws + 96 * MB);
    ushort* bVt = bWq;   // reuse after Wq GEMM done
    ushort* bQ  = bAq;   // reuse after Q GEMM done
    ushort* bK  = bAv;   // reuse after V GEMM done
    ushort* bAo = bAk;   // reuse after K GEMM done

    const int ncv = T_LEN * EMB;              // 4M elems
    const int cvb = ncv / (256 * 8);          // 2048 blocks
    f32_to_bf16_k<<<cvb, 256, 0, stream>>>(Wq, bWq, ncv);
    f32_to_bf16_k<<<cvb, 256, 0, stream>>>(Wk, bWk, ncv);
    f32_to_bf16_k<<<cvb, 256, 0, stream>>>(Wv, bWv, ncv);
    f32_to_bf16_k<<<cvb, 256, 0, stream>>>(Wo, bWo, ncv);
    f32_to_bf16_k<<<cvb, 256, 0, stream>>>(query, bAq, ncv);
    f32_to_bf16_k<<<cvb, 256, 0, stream>>>(key,   bAk, ncv);
    f32_to_bf16_k<<<cvb, 256, 0, stream>>>(value, bAv, ncv);

    dim3 gGemm(EMB / GBN, T_LEN / GBM);       // 16 x 16
    gemm_bf16_nt<<<gGemm, 256, 0, stream>>>(bAq, bWq, bq, q_ws, T_LEN, EMB, EMB);
    gemm_bf16_nt<<<gGemm, 256, 0, stream>>>(bAk, bWk, bk, k_ws, T_LEN, EMB, EMB);
    gemm_bf16_nt<<<gGemm, 256, 0, stream>>>(bAv, bWv, bv, v_ws, T_LEN, EMB, EMB);

    const int nrot = T_LEN * NH * HALF;
    rotary_kernel<<<nrot / 256, 256, 0, stream>>>(q_ws, k_ws, sinp, cosp, xscale);

    // convert rotated Q,K to bf16; transpose+convert V to [e][t]
    f32_to_bf16_k<<<cvb, 256, 0, stream>>>(q_ws, bQ, ncv);
    f32_to_bf16_k<<<cvb, 256, 0, stream>>>(k_ws, bK, ncv);
    dim3 gTr(T_LEN / 64, EMB / 64);
    transpose_f32_bf16<<<gTr, 256, 0, stream>>>(v_ws, bVt);

    dim3 gFlash(NH, T_LEN / 64);
    flash_attn_mfma<<<gFlash, 256, 0, stream>>>(bQ, bK, bVt, bAo);

    gemm_bf16_nt<<<gGemm, 256, 0, stream>>>(bAo, bWo, bo, out, T_LEN, EMB, EMB);
}

// Round 4
// 262.190 us; speedup vs baseline: 7.5613x; 1.1428x over previous
//
#include <hip/hip_runtime.h>
#include <hip/hip_bf16.h>
#include <math.h>

// Problem constants (fixed by harness)
#define T_LEN 2048
#define EMB   2048
#define NH    32
#define HD    64
#define HALF  32

typedef __attribute__((ext_vector_type(8))) short short8v;   // 8 bf16 (4 VGPR)
typedef __attribute__((ext_vector_type(4))) float floatx4;   // MFMA C/D

// async global->LDS, 16B per lane. LDS dest is wave-uniform base + lane*16.
__device__ inline void gload_lds16(const void* g, void* l) {
    __builtin_amdgcn_global_load_lds(
        (const __attribute__((address_space(1))) unsigned int*)g,
        (__attribute__((address_space(3))) unsigned int*)l,
        16, 0, 0);
}

__device__ inline ushort f2bf(float x) {
    union { float f; unsigned u; } c; c.f = x;
    const unsigned r = c.u + 0x7FFFu + ((c.u >> 16) & 1u);  // RNE
    return (ushort)(r >> 16);
}

// ---------------------------------------------------------------------------
// One-shot fp32->bf16 conversion of all 7 tensors into a contiguous bf16
// workspace: [Wq|Wk|Wv|Wo|query|key|value], each 4M elems (8 MB bf16).
// t is block-uniform (each block covers 2048 consecutive elems).
// ---------------------------------------------------------------------------
__global__ __launch_bounds__(256) void conv_all(
    const float* __restrict__ s0, const float* __restrict__ s1,
    const float* __restrict__ s2, const float* __restrict__ s3,
    const float* __restrict__ s4, const float* __restrict__ s5,
    const float* __restrict__ s6, ushort* __restrict__ dst)
{
    const int idx = blockIdx.x * 256 + threadIdx.x;   // 7 * 2^19 threads
    const int t = idx >> 19;
    const int r = (idx & 524287) * 8;
    const float* in = t == 0 ? s0 : t == 1 ? s1 : t == 2 ? s2 : t == 3 ? s3
                    : t == 4 ? s4 : t == 5 ? s5 : s6;
    const float4 v0 = *reinterpret_cast<const float4*>(&in[r]);
    const float4 v1 = *reinterpret_cast<const float4*>(&in[r + 4]);
    ushort o[8];
    o[0] = f2bf(v0.x); o[1] = f2bf(v0.y); o[2] = f2bf(v0.z); o[3] = f2bf(v0.w);
    o[4] = f2bf(v1.x); o[5] = f2bf(v1.y); o[6] = f2bf(v1.z); o[7] = f2bf(v1.w);
    *reinterpret_cast<uint4*>(&dst[(size_t)t * 4194304 + r]) =
        *reinterpret_cast<const uint4*>(o);
}

// ---------------------------------------------------------------------------
// bf16 MFMA GEMM (m97 structure), C = A * B^T + bias, M=N=K=2048, with fused
// epilogues:
//   EPI=0: fp32 store (final output projection)
//   EPI=1: xPos rotary (scale = xscale * scale_attention(t) * HD^-0.5) -> bf16 Q
//   EPI=2: xPos rotary (scale = 1/xscale) -> bf16 K
//   EPI=3: transposed bf16 store out[col][row] (V -> Vt)
// Rotary pair (2p,2p+1) = adjacent cols = lanes lm, lm^1 -> __shfl_xor(v,1).
// C/D layout: col = lane&15, row = (lane>>4)*4 + reg  [m89/m91 verified].
// ---------------------------------------------------------------------------
#define GBM 128
#define GBN 128
#define GBK 64

template<int EPI>
__global__ __launch_bounds__(256) void gemm_epi(
    const ushort* __restrict__ A,   // [2048][2048] bf16
    const ushort* __restrict__ B,   // [2048][2048] bf16 (row = out col)
    const float* __restrict__ bias,
    void* __restrict__ Cout,
    const float* __restrict__ sinp,
    const float* __restrict__ cosp,
    const float* __restrict__ xscale)
{
    __shared__ ushort As[GBM * GBK];
    __shared__ ushort Bs[GBN * GBK];
    const int tid  = threadIdx.x;
    const int lane = tid & 63;
    const int wid  = tid >> 6;
    const int bm = blockIdx.y * GBM;
    const int bn = blockIdx.x * GBN;
    const int wr = (wid >> 1) * 64;
    const int wc = (wid & 1) * 64;

    floatx4 acc[4][4] = {};

    const int lrow  = lane >> 3;
    const int lcolb = (lane & 7) * 8;

    for (int k0 = 0; k0 < EMB; k0 += GBK) {
        #pragma unroll
        for (int c = 0; c < 4; ++c) {
            const int chunk = wid * 4 + c;
            const int row = chunk * 8 + lrow;
            gload_lds16(&A[(size_t)(bm + row) * EMB + k0 + lcolb], &As[chunk * 512]);
            gload_lds16(&B[(size_t)(bn + row) * EMB + k0 + lcolb], &Bs[chunk * 512]);
        }
        __syncthreads();
        #pragma unroll
        for (int kk = 0; kk < 2; ++kk) {
            short8v a[4], b[4];
            #pragma unroll
            for (int m = 0; m < 4; ++m)
                a[m] = *reinterpret_cast<const short8v*>(
                    &As[(wr + m * 16 + (lane & 15)) * GBK + kk * 32 + (lane >> 4) * 8]);
            #pragma unroll
            for (int n = 0; n < 4; ++n)
                b[n] = *reinterpret_cast<const short8v*>(
                    &Bs[(wc + n * 16 + (lane & 15)) * GBK + kk * 32 + (lane >> 4) * 8]);
            #pragma unroll
            for (int m = 0; m < 4; ++m)
                #pragma unroll
                for (int n = 0; n < 4; ++n)
                    acc[m][n] = __builtin_amdgcn_mfma_f32_16x16x32_bf16(
                        a[m], b[n], acc[m][n], 0, 0, 0);
        }
        __syncthreads();
    }

    const int cr = (lane >> 4) * 4;
    const int cc = lane & 15;
    #pragma unroll
    for (int m = 0; m < 4; ++m) {
        #pragma unroll
        for (int n = 0; n < 4; ++n) {
            const int col = bn + wc + n * 16 + cc;
            const float bz = bias[col];
            if constexpr (EPI == 0) {
                float* C = (float*)Cout;
                #pragma unroll
                for (int j = 0; j < 4; ++j) {
                    const int row = bm + wr + m * 16 + cr + j;
                    C[(size_t)row * EMB + col] = acc[m][n][j] + bz;
                }
            } else if constexpr (EPI == 3) {
                ushort* Vt = (ushort*)Cout;
                const int row0 = bm + wr + m * 16 + cr;
                ushort o4[4];
                #pragma unroll
                for (int j = 0; j < 4; ++j)
                    o4[j] = f2bf(acc[m][n][j] + bz);
                *reinterpret_cast<uint2*>(&Vt[(size_t)col * T_LEN + row0]) =
                    *reinterpret_cast<const uint2*>(o4);
            } else {
                ushort* O = (ushort*)Cout;
                const int p = (col & 63) >> 1;
                const bool even = (col & 1) == 0;
                #pragma unroll
                for (int j = 0; j < 4; ++j) {
                    const int row = bm + wr + m * 16 + cr + j;
                    const float v = acc[m][n][j] + bz;
                    const float pv = __shfl_xor(v, 1);
                    const float s  = sinp[row * HALF + p];
                    const float c  = cosp[row * HALF + p];
                    const float xs = xscale[row * HALF + p];
                    float scale;
                    if constexpr (EPI == 1) {
                        float sa = 1.f;
                        if (row >= 2) {
                            const float lv = __logf((float)row) * 0.14426950408889634f; // 1/ln(1024)
                            sa = lv > 1.f ? lv : 1.f;
                        }
                        scale = xs * sa * 0.125f;   // * HD^-0.5
                    } else {
                        scale = 1.0f / xs;
                    }
                    const float C_ = c * scale, S_ = s * scale;
                    const float outv = even ? v * C_ - pv * S_ : v * C_ + pv * S_;
                    O[(size_t)row * EMB + col] = f2bf(outv);
                }
            }
        }
    }
}

// ---------------------------------------------------------------------------
// MFMA flash attention (bf16, causal, online softmax), 2-phase pipelined:
// prefetch next K/V tile (global_load_lds into buf^1) BEFORE computing the
// current tile; single __syncthreads per tile (drains vmcnt + syncs).
// Defer-max (T13): skip O-rescale while per-row max growth <= 8.
// Swapped QK^T -> lane-local scores; P staged per-wave in swizzled LDS.
// ---------------------------------------------------------------------------
__global__ __launch_bounds__(256) void flash_attn_mfma(
    const ushort* __restrict__ Qb,   // [T][EMB] bf16 (rotary+scaled)
    const ushort* __restrict__ Kb,   // [T][EMB] bf16 (rotary)
    const ushort* __restrict__ Vt,   // [EMB][T] bf16 (per-head [d][t])
    ushort* __restrict__ Ob)         // [T][EMB] bf16
{
    __shared__ ushort Ks[2][64 * 64];    // 2 x 8 KB
    __shared__ ushort Vs[2][64 * 64];    // 2 x 8 KB
    __shared__ ushort Ps[4][16 * 64];    // 8 KB (2 KB per wave)

    const int h   = blockIdx.x;
    const int qb  = blockIdx.y;
    const int tid = threadIdx.x;
    const int lane = tid & 63;
    const int wid  = tid >> 6;
    const int qrow_w = qb * 64 + wid * 16;
    const int lm = lane & 15;
    const int lg = lane >> 4;

    short8v qf[2];
    {
        const ushort* qp = &Qb[(size_t)(qrow_w + lm) * EMB + h * HD + lg * 8];
        qf[0] = *reinterpret_cast<const short8v*>(qp);
        qf[1] = *reinterpret_cast<const short8v*>(qp + 32);
    }

    floatx4 oacc[4] = {};
    float m = -1e30f, l = 0.f;

    const int srow = lane >> 3;
    const int schk = lane & 7;

    // prologue: stage tile 0 into buffer 0
    {
        #pragma unroll
        for (int i = 0; i < 2; ++i) {
            const int slot = wid * 2 + i;
            const int row  = slot * 8 + srow;
            const int cswz = (schk ^ (row & 7)) * 8;
            gload_lds16(&Kb[(size_t)row * EMB + h * HD + cswz], &Ks[0][slot * 512]);
            gload_lds16(&Vt[(size_t)(h * HD + row) * T_LEN + cswz], &Vs[0][slot * 512]);
        }
    }
    __syncthreads();

    for (int kb = 0; kb <= qb; ++kb) {
        const int cur = kb & 1;
        // prefetch next tile into the other buffer (overlaps with compute)
        if (kb < qb) {
            const int nkb = kb + 1;
            #pragma unroll
            for (int i = 0; i < 2; ++i) {
                const int slot = wid * 2 + i;
                const int row  = slot * 8 + srow;
                const int cswz = (schk ^ (row & 7)) * 8;
                gload_lds16(&Kb[(size_t)(nkb * 64 + row) * EMB + h * HD + cswz],
                            &Ks[cur ^ 1][slot * 512]);
                gload_lds16(&Vt[(size_t)(h * HD + row) * T_LEN + nkb * 64 + cswz],
                            &Vs[cur ^ 1][slot * 512]);
            }
        }

        // ---- QK^T (swapped): 4 s-tiles x 2 k-chunks
        float sv[16];
        #pragma unroll
        for (int t = 0; t < 4; ++t) {
            floatx4 sacc = {};
            const int srow_l = t * 16 + lm;
            const char* krow = reinterpret_cast<const char*>(Ks[cur]) + srow_l * 128;
            const int swz = (srow_l & 7) << 4;
            #pragma unroll
            for (int kk = 0; kk < 2; ++kk) {
                const int cb = (kk * 64 + lg * 16) ^ swz;
                short8v kf = *reinterpret_cast<const short8v*>(krow + cb);
                sacc = __builtin_amdgcn_mfma_f32_16x16x32_bf16(kf, qf[kk], sacc, 0, 0, 0);
            }
            sv[t * 4 + 0] = sacc[0]; sv[t * 4 + 1] = sacc[1];
            sv[t * 4 + 2] = sacc[2]; sv[t * 4 + 3] = sacc[3];
        }

        // causal mask on the diagonal block
        const int qg = qrow_w + lm;
        if (kb == qb) {
            #pragma unroll
            for (int t = 0; t < 4; ++t)
                #pragma unroll
                for (int r = 0; r < 4; ++r) {
                    const int sg = kb * 64 + t * 16 + lg * 4 + r;
                    if (sg > qg) sv[t * 4 + r] = -1e30f;
                }
        }

        // ---- online softmax with defer-max
        float mx = sv[0];
        #pragma unroll
        for (int i = 1; i < 16; ++i) mx = fmaxf(mx, sv[i]);
        mx = fmaxf(mx, __shfl_xor(mx, 16));
        mx = fmaxf(mx, __shfl_xor(mx, 32));
        float corr = 1.f;
        if (!__all(mx - m <= 8.f)) {
            const float mnew = fmaxf(m, mx);
            corr = __expf(m - mnew);
            m = mnew;
            float corr4[4];
            #pragma unroll
            for (int r = 0; r < 4; ++r)
                corr4[r] = __shfl(corr, lg * 4 + r);
            #pragma unroll
            for (int td = 0; td < 4; ++td)
                #pragma unroll
                for (int r = 0; r < 4; ++r)
                    oacc[td][r] *= corr4[r];
        }
        float ps = 0.f;
        ushort pb[16];
        #pragma unroll
        for (int i = 0; i < 16; ++i) {
            const float p = __expf(sv[i] - m);
            ps += p;
            pb[i] = f2bf(p);
        }
        ps += __shfl_xor(ps, 16);
        ps += __shfl_xor(ps, 32);
        l = l * corr + ps;

        // ---- write P to per-wave LDS [q=lm][s], swizzled
        {
            char* pbase = reinterpret_cast<char*>(&Ps[wid][0]) + lm * 128;
            const int swz = (lm & 7) << 4;
            #pragma unroll
            for (int t = 0; t < 4; ++t) {
                uint2 w;
                w.x = (unsigned)pb[t * 4 + 0] | ((unsigned)pb[t * 4 + 1] << 16);
                w.y = (unsigned)pb[t * 4 + 2] | ((unsigned)pb[t * 4 + 3] << 16);
                const int cb = (t * 32 + lg * 8) ^ swz;
                *reinterpret_cast<uint2*>(pbase + cb) = w;
            }
        }

        // ---- PV: a = P rows (q), b = Vt rows (d)
        const char* pwave = reinterpret_cast<const char*>(&Ps[wid][0]);
        #pragma unroll
        for (int kk = 0; kk < 2; ++kk) {
            const int acb = (kk * 64 + lg * 16) ^ ((lm & 7) << 4);
            short8v pa = *reinterpret_cast<const short8v*>(pwave + lm * 128 + acb);
            #pragma unroll
            for (int td = 0; td < 4; ++td) {
                const int d = td * 16 + lm;
                const int bcb = (kk * 64 + lg * 16) ^ ((d & 7) << 4);
                short8v vb = *reinterpret_cast<const short8v*>(
                    reinterpret_cast<const char*>(Vs[cur]) + d * 128 + bcb);
                oacc[td] = __builtin_amdgcn_mfma_f32_16x16x32_bf16(pa, vb, oacc[td], 0, 0, 0);
            }
        }

        __syncthreads();   // drains prefetch (vmcnt0) + all waves done with buf[cur]
    }

    // ---- epilogue: normalize by l, store bf16
    float invl[4];
    #pragma unroll
    for (int r = 0; r < 4; ++r)
        invl[r] = 1.f / __shfl(l, lg * 4 + r);
    #pragma unroll
    for (int td = 0; td < 4; ++td) {
        #pragma unroll
        for (int r = 0; r < 4; ++r) {
            const int trow = qrow_w + lg * 4 + r;
            const int col  = h * HD + td * 16 + lm;
            Ob[(size_t)trow * EMB + col] = f2bf(oacc[td][r] * invl[r]);
        }
    }
}

// ---------------------------------------------------------------------------
// Launch. 6 dispatches. Workspace (88 MB), all bf16:
//   +0  bWq  +8  bWk  +16 bWv  +24 bWo  +32 bAq  +40 bAk  +48 bAv
//   +56 bQ   +64 bK   +72 bVt  +80 bAo
// ---------------------------------------------------------------------------
extern "C" void kernel_launch(void* const* d_in, const int* in_sizes, int n_in,
                              void* d_out, int out_size, void* d_ws, size_t ws_size,
                              hipStream_t stream) {
    const float* query = (const float*)d_in[0];
    const float* key   = (const float*)d_in[1];
    const float* value = (const float*)d_in[2];
    const float* Wq = (const float*)d_in[3];
    const float* bq = (const float*)d_in[4];
    const float* Wk = (const float*)d_in[5];
    const float* bk = (const float*)d_in[6];
    const float* Wv = (const float*)d_in[7];
    const float* bv = (const float*)d_in[8];
    const float* Wo = (const float*)d_in[9];
    const float* bo = (const float*)d_in[10];
    const float* sinp   = (const float*)d_in[11];
    const float* cosp   = (const float*)d_in[12];
    const float* xscale = (const float*)d_in[13];
    float* out = (float*)d_out;

    const size_t MB = 1024 * 1024;
    char* ws = (char*)d_ws;
    ushort* bWq = (ushort*)(ws + 0 * MB);
    ushort* bWk = (ushort*)(ws + 8 * MB);
    ushort* bWv = (ushort*)(ws + 16 * MB);
    ushort* bWo = (ushort*)(ws + 24 * MB);
    ushort* bAq = (ushort*)(ws + 32 * MB);
    ushort* bAk = (ushort*)(ws + 40 * MB);
    ushort* bAv = (ushort*)(ws + 48 * MB);
    ushort* bQ  = (ushort*)(ws + 56 * MB);
    ushort* bK  = (ushort*)(ws + 64 * MB);
    ushort* bVt = (ushort*)(ws + 72 * MB);
    ushort* bAo = (ushort*)(ws + 80 * MB);

    // 1) convert all inputs to bf16 (dst order matches bWq..bAv layout)
    conv_all<<<7 * 524288 / 256, 256, 0, stream>>>(
        Wq, Wk, Wv, Wo, query, key, value, bWq);

    // 2-4) projections with fused epilogues
    dim3 gGemm(EMB / GBN, T_LEN / GBM);       // 16 x 16
    gemm_epi<1><<<gGemm, 256, 0, stream>>>(bAq, bWq, bq, bQ,  sinp, cosp, xscale);
    gemm_epi<2><<<gGemm, 256, 0, stream>>>(bAk, bWk, bk, bK,  sinp, cosp, xscale);
    gemm_epi<3><<<gGemm, 256, 0, stream>>>(bAv, bWv, bv, bVt, nullptr, nullptr, nullptr);

    // 5) flash attention
    dim3 gFlash(NH, T_LEN / 64);
    flash_attn_mfma<<<gFlash, 256, 0, stream>>>(bQ, bK, bVt, bAo);

    // 6) output projection (fp32 out)
    gemm_epi<0><<<gGemm, 256, 0, stream>>>(bAo, bWo, bo, out, nullptr, nullptr, nullptr);
}

// Round 5
// 226.282 us; speedup vs baseline: 8.7611x; 1.1587x over previous
//
#include <hip/hip_runtime.h>
#include <hip/hip_bf16.h>
#include <math.h>

// Problem constants (fixed by harness)
#define T_LEN 2048
#define EMB   2048
#define NH    32
#define HD    64
#define HALF  32

typedef __attribute__((ext_vector_type(8))) short short8v;   // 8 bf16 (4 VGPR)
typedef __attribute__((ext_vector_type(4))) float floatx4;   // MFMA C/D

// async global->LDS, 16B per lane. LDS dest is wave-uniform base + lane*16.
__device__ inline void gload_lds16(const void* g, void* l) {
    __builtin_amdgcn_global_load_lds(
        (const __attribute__((address_space(1))) unsigned int*)g,
        (__attribute__((address_space(3))) unsigned int*)l,
        16, 0, 0);
}

__device__ inline ushort f2bf(float x) {
    union { float f; unsigned u; } c; c.f = x;
    const unsigned r = c.u + 0x7FFFu + ((c.u >> 16) & 1u);  // RNE
    return (ushort)(r >> 16);
}

// ---------------------------------------------------------------------------
// One-shot fp32->bf16 conversion of all 7 tensors into a contiguous bf16
// workspace: [Wq|Wk|Wv|Wo|query|key|value], each 4M elems (8 MB bf16).
// ---------------------------------------------------------------------------
__global__ __launch_bounds__(256) void conv_all(
    const float* __restrict__ s0, const float* __restrict__ s1,
    const float* __restrict__ s2, const float* __restrict__ s3,
    const float* __restrict__ s4, const float* __restrict__ s5,
    const float* __restrict__ s6, ushort* __restrict__ dst)
{
    const int idx = blockIdx.x * 256 + threadIdx.x;   // 7 * 2^19 threads
    const int t = idx >> 19;
    const int r = (idx & 524287) * 8;
    const float* in = t == 0 ? s0 : t == 1 ? s1 : t == 2 ? s2 : t == 3 ? s3
                    : t == 4 ? s4 : t == 5 ? s5 : s6;
    const float4 v0 = *reinterpret_cast<const float4*>(&in[r]);
    const float4 v1 = *reinterpret_cast<const float4*>(&in[r + 4]);
    ushort o[8];
    o[0] = f2bf(v0.x); o[1] = f2bf(v0.y); o[2] = f2bf(v0.z); o[3] = f2bf(v0.w);
    o[4] = f2bf(v1.x); o[5] = f2bf(v1.y); o[6] = f2bf(v1.z); o[7] = f2bf(v1.w);
    *reinterpret_cast<uint4*>(&dst[(size_t)t * 4194304 + r]) =
        *reinterpret_cast<const uint4*>(o);
}

// ---------------------------------------------------------------------------
// m97-structure GEMM core macros (128x128 tile, BK=64, 4 waves, 16x16x32 bf16)
// C/D layout: col = lane&15, row = (lane>>4)*4 + reg  [m89/m91 verified].
// ---------------------------------------------------------------------------
#define GBM 128
#define GBN 128
#define GBK 64

// ---------------------------------------------------------------------------
// Fused QKV projection GEMM: one dispatch, 768 blocks (3 blocks/CU) to fix
// the 1-wave/SIMD occupancy starvation of 3 separate N=2048 launches.
//   Astack = [bAq|bAk|bAv] (3 x 4M bf16), Wstack = [Wq|Wk|Wv] (3 x 4M bf16)
//   which = blockIdx.x>>4 selects matrix; epilogues:
//     which=0: xPos rotary * xscale * scale_attention * HD^-0.5 -> bQ
//     which=1: xPos rotary * 1/xscale                            -> bK
//     which=2: transposed store Vt[col][row]                     -> bVt
// Rotary pair (2p,2p+1) = adjacent cols = lanes lm, lm^1 -> __shfl_xor(v,1).
// ---------------------------------------------------------------------------
__global__ __launch_bounds__(256) void gemm_qkv(
    const ushort* __restrict__ Astack,
    const ushort* __restrict__ Wstack,
    const float* __restrict__ bq, const float* __restrict__ bk,
    const float* __restrict__ bv,
    ushort* __restrict__ outQ, ushort* __restrict__ outK,
    ushort* __restrict__ outVt,
    const float* __restrict__ sinp, const float* __restrict__ cosp,
    const float* __restrict__ xscale)
{
    __shared__ ushort As[GBM * GBK];
    __shared__ ushort Bs[GBN * GBK];
    const int tid  = threadIdx.x;
    const int lane = tid & 63;
    const int wid  = tid >> 6;
    const int which = blockIdx.x >> 4;            // 0=Q 1=K 2=V
    const int bn = (blockIdx.x & 15) * GBN;
    const int bm = blockIdx.y * GBM;
    const ushort* A = Astack + (size_t)which * 4194304;
    const ushort* B = Wstack + (size_t)which * 4194304;
    const float* bias = which == 0 ? bq : which == 1 ? bk : bv;

    const int wr = (wid >> 1) * 64;
    const int wc = (wid & 1) * 64;

    floatx4 acc[4][4] = {};

    const int lrow  = lane >> 3;
    const int lcolb = (lane & 7) * 8;

    for (int k0 = 0; k0 < EMB; k0 += GBK) {
        #pragma unroll
        for (int c = 0; c < 4; ++c) {
            const int chunk = wid * 4 + c;
            const int row = chunk * 8 + lrow;
            gload_lds16(&A[(size_t)(bm + row) * EMB + k0 + lcolb], &As[chunk * 512]);
            gload_lds16(&B[(size_t)(bn + row) * EMB + k0 + lcolb], &Bs[chunk * 512]);
        }
        __syncthreads();
        #pragma unroll
        for (int kk = 0; kk < 2; ++kk) {
            short8v a[4], b[4];
            #pragma unroll
            for (int m = 0; m < 4; ++m)
                a[m] = *reinterpret_cast<const short8v*>(
                    &As[(wr + m * 16 + (lane & 15)) * GBK + kk * 32 + (lane >> 4) * 8]);
            #pragma unroll
            for (int n = 0; n < 4; ++n)
                b[n] = *reinterpret_cast<const short8v*>(
                    &Bs[(wc + n * 16 + (lane & 15)) * GBK + kk * 32 + (lane >> 4) * 8]);
            #pragma unroll
            for (int m = 0; m < 4; ++m)
                #pragma unroll
                for (int n = 0; n < 4; ++n)
                    acc[m][n] = __builtin_amdgcn_mfma_f32_16x16x32_bf16(
                        a[m], b[n], acc[m][n], 0, 0, 0);
        }
        __syncthreads();
    }

    const int cr = (lane >> 4) * 4;
    const int cc = lane & 15;
    #pragma unroll
    for (int m = 0; m < 4; ++m) {
        #pragma unroll
        for (int n = 0; n < 4; ++n) {
            const int col = bn + wc + n * 16 + cc;
            const float bz = bias[col];
            if (which == 2) {
                // V: transposed bf16 store Vt[col][row0..row0+3]
                const int row0 = bm + wr + m * 16 + cr;
                ushort o4[4];
                #pragma unroll
                for (int j = 0; j < 4; ++j)
                    o4[j] = f2bf(acc[m][n][j] + bz);
                *reinterpret_cast<uint2*>(&outVt[(size_t)col * T_LEN + row0]) =
                    *reinterpret_cast<const uint2*>(o4);
            } else {
                ushort* O = which == 0 ? outQ : outK;
                const int p = (col & 63) >> 1;
                const bool even = (col & 1) == 0;
                #pragma unroll
                for (int j = 0; j < 4; ++j) {
                    const int row = bm + wr + m * 16 + cr + j;
                    const float v = acc[m][n][j] + bz;
                    const float pv = __shfl_xor(v, 1);
                    const float s  = sinp[row * HALF + p];
                    const float c  = cosp[row * HALF + p];
                    const float xs = xscale[row * HALF + p];
                    float scale;
                    if (which == 0) {
                        float sa = 1.f;
                        if (row >= 2) {
                            const float lv = __logf((float)row) * 0.14426950408889634f;
                            sa = lv > 1.f ? lv : 1.f;
                        }
                        scale = xs * sa * 0.125f;   // * HD^-0.5
                    } else {
                        scale = 1.0f / xs;
                    }
                    const float C_ = c * scale, S_ = s * scale;
                    const float outv = even ? v * C_ - pv * S_ : v * C_ + pv * S_;
                    O[(size_t)row * EMB + col] = f2bf(outv);
                }
            }
        }
    }
}

// ---------------------------------------------------------------------------
// Output projection GEMM (fp32 out): C = A * B^T + bias
// ---------------------------------------------------------------------------
__global__ __launch_bounds__(256) void gemm_out(
    const ushort* __restrict__ A,
    const ushort* __restrict__ B,
    const float* __restrict__ bias,
    float* __restrict__ C)
{
    __shared__ ushort As[GBM * GBK];
    __shared__ ushort Bs[GBN * GBK];
    const int tid  = threadIdx.x;
    const int lane = tid & 63;
    const int wid  = tid >> 6;
    const int bm = blockIdx.y * GBM;
    const int bn = blockIdx.x * GBN;
    const int wr = (wid >> 1) * 64;
    const int wc = (wid & 1) * 64;

    floatx4 acc[4][4] = {};

    const int lrow  = lane >> 3;
    const int lcolb = (lane & 7) * 8;

    for (int k0 = 0; k0 < EMB; k0 += GBK) {
        #pragma unroll
        for (int c = 0; c < 4; ++c) {
            const int chunk = wid * 4 + c;
            const int row = chunk * 8 + lrow;
            gload_lds16(&A[(size_t)(bm + row) * EMB + k0 + lcolb], &As[chunk * 512]);
            gload_lds16(&B[(size_t)(bn + row) * EMB + k0 + lcolb], &Bs[chunk * 512]);
        }
        __syncthreads();
        #pragma unroll
        for (int kk = 0; kk < 2; ++kk) {
            short8v a[4], b[4];
            #pragma unroll
            for (int m = 0; m < 4; ++m)
                a[m] = *reinterpret_cast<const short8v*>(
                    &As[(wr + m * 16 + (lane & 15)) * GBK + kk * 32 + (lane >> 4) * 8]);
            #pragma unroll
            for (int n = 0; n < 4; ++n)
                b[n] = *reinterpret_cast<const short8v*>(
                    &Bs[(wc + n * 16 + (lane & 15)) * GBK + kk * 32 + (lane >> 4) * 8]);
            #pragma unroll
            for (int m = 0; m < 4; ++m)
                #pragma unroll
                for (int n = 0; n < 4; ++n)
                    acc[m][n] = __builtin_amdgcn_mfma_f32_16x16x32_bf16(
                        a[m], b[n], acc[m][n], 0, 0, 0);
        }
        __syncthreads();
    }

    const int cr = (lane >> 4) * 4;
    const int cc = lane & 15;
    #pragma unroll
    for (int m = 0; m < 4; ++m) {
        #pragma unroll
        for (int n = 0; n < 4; ++n) {
            const int col = bn + wc + n * 16 + cc;
            const float bz = bias[col];
            #pragma unroll
            for (int j = 0; j < 4; ++j) {
                const int row = bm + wr + m * 16 + cr + j;
                C[(size_t)row * EMB + col] = acc[m][n][j] + bz;
            }
        }
    }
}

// ---------------------------------------------------------------------------
// MFMA flash attention (bf16, causal, online softmax), 2-phase pipelined,
// defer-max (T13). P packed via __float22bfloat162_rn (compiler emits
// v_cvt_pk_bf16_f32 — replaces ~80 VALU ops/tile of manual RNE packing).
// Heavy q-blocks launched first (LPT) to shave the causal imbalance tail.
// ---------------------------------------------------------------------------
__global__ __launch_bounds__(256) void flash_attn_mfma(
    const ushort* __restrict__ Qb,   // [T][EMB] bf16 (rotary+scaled)
    const ushort* __restrict__ Kb,   // [T][EMB] bf16 (rotary)
    const ushort* __restrict__ Vt,   // [EMB][T] bf16 (per-head [d][t])
    ushort* __restrict__ Ob)         // [T][EMB] bf16
{
    __shared__ ushort Ks[2][64 * 64];    // 2 x 8 KB
    __shared__ ushort Vs[2][64 * 64];    // 2 x 8 KB
    __shared__ ushort Ps[4][16 * 64];    // 8 KB (2 KB per wave)

    const int h   = blockIdx.x;
    const int qb  = (T_LEN / 64 - 1) - blockIdx.y;   // LPT: heavy blocks first
    const int tid = threadIdx.x;
    const int lane = tid & 63;
    const int wid  = tid >> 6;
    const int qrow_w = qb * 64 + wid * 16;
    const int lm = lane & 15;
    const int lg = lane >> 4;

    short8v qf[2];
    {
        const ushort* qp = &Qb[(size_t)(qrow_w + lm) * EMB + h * HD + lg * 8];
        qf[0] = *reinterpret_cast<const short8v*>(qp);
        qf[1] = *reinterpret_cast<const short8v*>(qp + 32);
    }

    floatx4 oacc[4] = {};
    float m = -1e30f, l = 0.f;

    const int srow = lane >> 3;
    const int schk = lane & 7;

    // prologue: stage tile 0 into buffer 0
    {
        #pragma unroll
        for (int i = 0; i < 2; ++i) {
            const int slot = wid * 2 + i;
            const int row  = slot * 8 + srow;
            const int cswz = (schk ^ (row & 7)) * 8;
            gload_lds16(&Kb[(size_t)row * EMB + h * HD + cswz], &Ks[0][slot * 512]);
            gload_lds16(&Vt[(size_t)(h * HD + row) * T_LEN + cswz], &Vs[0][slot * 512]);
        }
    }
    __syncthreads();

    for (int kb = 0; kb <= qb; ++kb) {
        const int cur = kb & 1;
        // prefetch next tile into the other buffer (overlaps with compute)
        if (kb < qb) {
            const int nkb = kb + 1;
            #pragma unroll
            for (int i = 0; i < 2; ++i) {
                const int slot = wid * 2 + i;
                const int row  = slot * 8 + srow;
                const int cswz = (schk ^ (row & 7)) * 8;
                gload_lds16(&Kb[(size_t)(nkb * 64 + row) * EMB + h * HD + cswz],
                            &Ks[cur ^ 1][slot * 512]);
                gload_lds16(&Vt[(size_t)(h * HD + row) * T_LEN + nkb * 64 + cswz],
                            &Vs[cur ^ 1][slot * 512]);
            }
        }

        // ---- QK^T (swapped): 4 s-tiles x 2 k-chunks
        float sv[16];
        #pragma unroll
        for (int t = 0; t < 4; ++t) {
            floatx4 sacc = {};
            const int srow_l = t * 16 + lm;
            const char* krow = reinterpret_cast<const char*>(Ks[cur]) + srow_l * 128;
            const int swz = (srow_l & 7) << 4;
            #pragma unroll
            for (int kk = 0; kk < 2; ++kk) {
                const int cb = (kk * 64 + lg * 16) ^ swz;
                short8v kf = *reinterpret_cast<const short8v*>(krow + cb);
                sacc = __builtin_amdgcn_mfma_f32_16x16x32_bf16(kf, qf[kk], sacc, 0, 0, 0);
            }
            sv[t * 4 + 0] = sacc[0]; sv[t * 4 + 1] = sacc[1];
            sv[t * 4 + 2] = sacc[2]; sv[t * 4 + 3] = sacc[3];
        }

        // causal mask on the diagonal block
        const int qg = qrow_w + lm;
        if (kb == qb) {
            #pragma unroll
            for (int t = 0; t < 4; ++t)
                #pragma unroll
                for (int r = 0; r < 4; ++r) {
                    const int sg = kb * 64 + t * 16 + lg * 4 + r;
                    if (sg > qg) sv[t * 4 + r] = -1e30f;
                }
        }

        // ---- online softmax with defer-max
        float mx = sv[0];
        #pragma unroll
        for (int i = 1; i < 16; ++i) mx = fmaxf(mx, sv[i]);
        mx = fmaxf(mx, __shfl_xor(mx, 16));
        mx = fmaxf(mx, __shfl_xor(mx, 32));
        float corr = 1.f;
        if (!__all(mx - m <= 8.f)) {
            const float mnew = fmaxf(m, mx);
            corr = __expf(m - mnew);
            m = mnew;
            float corr4[4];
            #pragma unroll
            for (int r = 0; r < 4; ++r)
                corr4[r] = __shfl(corr, lg * 4 + r);
            #pragma unroll
            for (int td = 0; td < 4; ++td)
                #pragma unroll
                for (int r = 0; r < 4; ++r)
                    oacc[td][r] *= corr4[r];
        }
        float ps = 0.f;
        unsigned pw[8];
        #pragma unroll
        for (int i = 0; i < 8; ++i) {
            const float p0 = __expf(sv[2 * i + 0] - m);
            const float p1 = __expf(sv[2 * i + 1] - m);
            ps += p0 + p1;
            const __hip_bfloat162 h2 = __float22bfloat162_rn(make_float2(p0, p1));
            pw[i] = *reinterpret_cast<const unsigned*>(&h2);
        }
        ps += __shfl_xor(ps, 16);
        ps += __shfl_xor(ps, 32);
        l = l * corr + ps;

        // ---- write P to per-wave LDS [q=lm][s], swizzled
        {
            char* pbase = reinterpret_cast<char*>(&Ps[wid][0]) + lm * 128;
            const int swz = (lm & 7) << 4;
            #pragma unroll
            for (int t = 0; t < 4; ++t) {
                uint2 w;
                w.x = pw[2 * t + 0];
                w.y = pw[2 * t + 1];
                const int cb = (t * 32 + lg * 8) ^ swz;
                *reinterpret_cast<uint2*>(pbase + cb) = w;
            }
        }

        // ---- PV: a = P rows (q), b = Vt rows (d)
        const char* pwave = reinterpret_cast<const char*>(&Ps[wid][0]);
        #pragma unroll
        for (int kk = 0; kk < 2; ++kk) {
            const int acb = (kk * 64 + lg * 16) ^ ((lm & 7) << 4);
            short8v pa = *reinterpret_cast<const short8v*>(pwave + lm * 128 + acb);
            #pragma unroll
            for (int td = 0; td < 4; ++td) {
                const int d = td * 16 + lm;
                const int bcb = (kk * 64 + lg * 16) ^ ((d & 7) << 4);
                short8v vb = *reinterpret_cast<const short8v*>(
                    reinterpret_cast<const char*>(Vs[cur]) + d * 128 + bcb);
                oacc[td] = __builtin_amdgcn_mfma_f32_16x16x32_bf16(pa, vb, oacc[td], 0, 0, 0);
            }
        }

        __syncthreads();   // drains prefetch (vmcnt0) + all waves done with buf[cur]
    }

    // ---- epilogue: normalize by l, store bf16
    float invl[4];
    #pragma unroll
    for (int r = 0; r < 4; ++r)
        invl[r] = 1.f / __shfl(l, lg * 4 + r);
    #pragma unroll
    for (int td = 0; td < 4; ++td) {
        #pragma unroll
        for (int r = 0; r < 4; ++r) {
            const int trow = qrow_w + lg * 4 + r;
            const int col  = h * HD + td * 16 + lm;
            Ob[(size_t)trow * EMB + col] = f2bf(oacc[td][r] * invl[r]);
        }
    }
}

// ---------------------------------------------------------------------------
// Launch. 4 dispatches. Workspace (88 MB), all bf16:
//   +0  [Wq|Wk|Wv] (24MB, stacked for gemm_qkv)  +24 bWo
//   +32 [bAq|bAk|bAv] (24MB, stacked)
//   +56 bQ   +64 bK   +72 bVt  +80 bAo
// ---------------------------------------------------------------------------
extern "C" void kernel_launch(void* const* d_in, const int* in_sizes, int n_in,
                              void* d_out, int out_size, void* d_ws, size_t ws_size,
                              hipStream_t stream) {
    const float* query = (const float*)d_in[0];
    const float* key   = (const float*)d_in[1];
    const float* value = (const float*)d_in[2];
    const float* Wq = (const float*)d_in[3];
    const float* bq = (const float*)d_in[4];
    const float* Wk = (const float*)d_in[5];
    const float* bk = (const float*)d_in[6];
    const float* Wv = (const float*)d_in[7];
    const float* bv = (const float*)d_in[8];
    const float* Wo = (const float*)d_in[9];
    const float* bo = (const float*)d_in[10];
    const float* sinp   = (const float*)d_in[11];
    const float* cosp   = (const float*)d_in[12];
    const float* xscale = (const float*)d_in[13];
    float* out = (float*)d_out;

    const size_t MB = 1024 * 1024;
    char* ws = (char*)d_ws;
    ushort* bWqkv = (ushort*)(ws + 0 * MB);    // stacked [Wq|Wk|Wv]
    ushort* bWo   = (ushort*)(ws + 24 * MB);
    ushort* bAqkv = (ushort*)(ws + 32 * MB);   // stacked [Aq|Ak|Av]
    ushort* bQ  = (ushort*)(ws + 56 * MB);
    ushort* bK  = (ushort*)(ws + 64 * MB);
    ushort* bVt = (ushort*)(ws + 72 * MB);
    ushort* bAo = (ushort*)(ws + 80 * MB);

    // 1) convert all inputs to bf16 (dst order matches layout above)
    conv_all<<<7 * 524288 / 256, 256, 0, stream>>>(
        Wq, Wk, Wv, Wo, query, key, value, bWqkv);

    // 2) fused QKV projections + rotary/transpose epilogues (768 blocks)
    dim3 gQKV(48, T_LEN / GBM);
    gemm_qkv<<<gQKV, 256, 0, stream>>>(bAqkv, bWqkv, bq, bk, bv,
                                       bQ, bK, bVt, sinp, cosp, xscale);

    // 3) flash attention
    dim3 gFlash(NH, T_LEN / 64);
    flash_attn_mfma<<<gFlash, 256, 0, stream>>>(bQ, bK, bVt, bAo);

    // 4) output projection (fp32 out)
    dim3 gGemm(EMB / GBN, T_LEN / GBM);
    gemm_out<<<gGemm, 256, 0, stream>>>(bAo, bWo, bo, out);
}

// Round 6
// 198.433 us; speedup vs baseline: 9.9907x; 1.1403x over previous
//
#include <hip/hip_runtime.h>
#include <hip/hip_bf16.h>
#include <math.h>

// Problem constants (fixed by harness)
#define T_LEN 2048
#define EMB   2048
#define NH    32
#define HD    64
#define HALF  32

typedef __attribute__((ext_vector_type(8))) short short8v;   // 8 bf16 (4 VGPR)
typedef __attribute__((ext_vector_type(4))) float floatx4;   // MFMA C/D

// async global->LDS, 16B per lane. LDS dest is wave-uniform base + lane*16.
__device__ inline void gload_lds16(const void* g, void* l) {
    __builtin_amdgcn_global_load_lds(
        (const __attribute__((address_space(1))) unsigned int*)g,
        (__attribute__((address_space(3))) unsigned int*)l,
        16, 0, 0);
}

__device__ inline ushort f2bf(float x) {
    union { float f; unsigned u; } c; c.f = x;
    const unsigned r = c.u + 0x7FFFu + ((c.u >> 16) & 1u);  // RNE
    return (ushort)(r >> 16);
}

// raw barrier with compiler memory fences (NO vmcnt drain, unlike __syncthreads)
#define BARRIER() do { asm volatile("" ::: "memory"); \
    __builtin_amdgcn_s_barrier(); asm volatile("" ::: "memory"); } while (0)
#define VMW4() asm volatile("s_waitcnt vmcnt(4)" ::: "memory")

// ---------------------------------------------------------------------------
// One-shot fp32->bf16 conversion of all 7 tensors into a contiguous bf16
// workspace: [Wq|Wk|Wv|Wo|query|key|value], each 4M elems (8 MB bf16).
// ---------------------------------------------------------------------------
__global__ __launch_bounds__(256) void conv_all(
    const float* __restrict__ s0, const float* __restrict__ s1,
    const float* __restrict__ s2, const float* __restrict__ s3,
    const float* __restrict__ s4, const float* __restrict__ s5,
    const float* __restrict__ s6, ushort* __restrict__ dst)
{
    const int idx = blockIdx.x * 256 + threadIdx.x;   // 7 * 2^19 threads
    const int t = idx >> 19;
    const int r = (idx & 524287) * 8;
    const float* in = t == 0 ? s0 : t == 1 ? s1 : t == 2 ? s2 : t == 3 ? s3
                    : t == 4 ? s4 : t == 5 ? s5 : s6;
    const float4 v0 = *reinterpret_cast<const float4*>(&in[r]);
    const float4 v1 = *reinterpret_cast<const float4*>(&in[r + 4]);
    ushort o[8];
    o[0] = f2bf(v0.x); o[1] = f2bf(v0.y); o[2] = f2bf(v0.z); o[3] = f2bf(v0.w);
    o[4] = f2bf(v1.x); o[5] = f2bf(v1.y); o[6] = f2bf(v1.z); o[7] = f2bf(v1.w);
    *reinterpret_cast<uint4*>(&dst[(size_t)t * 4194304 + r]) =
        *reinterpret_cast<const uint4*>(o);
}

// ---------------------------------------------------------------------------
// QKV projection, 256x256-tile 8-phase pipelined GEMM (T2+T3+T4+T5).
// 512 threads = 8 waves (2M x 4N); per-wave output 128x64 (8 M-frags x 4
// N-frags of 16x16x32 bf16 MFMA); BK=64 (2 MFMA k-chunks).
// LDS 128 KiB: A[slot2][half2][128][64] + B[slot2][half2][128][64] bf16,
// XOR-swizzled (chunk ^= row&7) via pre-swizzled global source (linear LDS
// dest for global_load_lds) + swizzled ds_read — rule #21 involution pair.
// Schedule (iteration computes tiles t=2i -> slot0 and t+1 -> slot1):
//   ph0: read B-frags(slot0)+A m0-1; stage A0(t+1)      [A-slot1 freed prev ph7]
//   ph1: A m2-3;                     stage A1(t+1)
//   ph2: A m4-5;                     stage B0(t+2)      [B-slot0 freed ph0]
//   ph3: A m6-7;                     stage B1(t+2); MFMA; vmcnt(4); bar
//   ph4-7: same on slot1, staging A(t+2) (ph4/5: A-slot0 freed ph3) and
//          B(t+3) (ph6/7: B-slot1 freed ph4); vmcnt(4) at ph7.
// vmcnt(4) leaves exactly the 2 just-issued half-tiles (2 loads/wave each)
// in flight; with the closing barrier it guarantees every earlier half-tile
// is fully in LDS before its first reader phase (ledger in session notes).
// Raw s_barrier (no vmcnt(0) drain) — this is the whole point vs m97.
// ---------------------------------------------------------------------------
#define QBM 256
#define QBN 256
#define QBK 64

#define STAGE_A(tau, h) do {                                                   \
    const int _tc = ((tau) & 31) * 64;                                         \
    _Pragma("unroll") for (int _i = 0; _i < 2; ++_i) {                         \
        gload_lds16(&Ap[(size_t)(bm + (h) * 128 + wid * 16 + _i * 8 + rl) * 2048 + _tc + csw], \
                    &lds[((tau) & 1) * 16384 + (h) * 8192 + (wid * 16 + _i * 8) * 64]); \
    } } while (0)

#define STAGE_B(tau, h) do {                                                   \
    const int _tc = ((tau) & 31) * 64;                                         \
    _Pragma("unroll") for (int _i = 0; _i < 2; ++_i) {                         \
        gload_lds16(&Bp[(size_t)(bn + (h) * 128 + wid * 16 + _i * 8 + rl) * 2048 + _tc + csw], \
                    &lds[32768 + ((tau) & 1) * 16384 + (h) * 8192 + (wid * 16 + _i * 8) * 64]); \
    } } while (0)

// one phase: ds-read subtile, issue stage (__VA_ARGS__), barrier,
// prio-boosted 16-MFMA cluster, optional counted vmcnt, barrier.
#define PH(slot, mp, VMWSTMT, ...) do {                                        \
    if ((mp) == 0) {                                                           \
        _Pragma("unroll") for (int n = 0; n < 4; ++n) {                        \
            bf[n][0] = ldB(slot, n, 0);                                        \
            bf[n][1] = ldB(slot, n, 1);                                        \
        }                                                                      \
    }                                                                          \
    af[0][0] = ldA(slot, (mp) * 2, 0);     af[0][1] = ldA(slot, (mp) * 2, 1);  \
    af[1][0] = ldA(slot, (mp) * 2 + 1, 0); af[1][1] = ldA(slot, (mp) * 2 + 1, 1); \
    __VA_ARGS__;                                                               \
    BARRIER();                                                                 \
    __builtin_amdgcn_s_setprio(1);                                             \
    _Pragma("unroll") for (int mm = 0; mm < 2; ++mm)                           \
    _Pragma("unroll") for (int n = 0; n < 4; ++n)                              \
    _Pragma("unroll") for (int kk = 0; kk < 2; ++kk)                           \
        acc[(mp) * 2 + mm][n] = __builtin_amdgcn_mfma_f32_16x16x32_bf16(       \
            af[mm][kk], bf[n][kk], acc[(mp) * 2 + mm][n], 0, 0, 0);            \
    __builtin_amdgcn_s_setprio(0);                                             \
    VMWSTMT;                                                                   \
    BARRIER();                                                                 \
} while (0)

__global__ __launch_bounds__(512, 2) void gemm_qkv8(
    const ushort* __restrict__ Astack,   // [Aq|Ak|Av] bf16, each [2048][2048]
    const ushort* __restrict__ Wstack,   // [Wq|Wk|Wv] bf16, each [2048][2048]
    const float* __restrict__ bq, const float* __restrict__ bk,
    const float* __restrict__ bv,
    ushort* __restrict__ outQ, ushort* __restrict__ outK,
    ushort* __restrict__ outVt,
    const float* __restrict__ sinp, const float* __restrict__ cosp,
    const float* __restrict__ xscale)
{
    __shared__ ushort lds[65536];   // 128 KiB
    const int tid  = threadIdx.x;
    const int lane = tid & 63;
    const int wid  = tid >> 6;      // 0..7

    // XCD-chunked bijective remap: each XCD owns 3 consecutive W col-panels
    // (3 MB <= 4 MB L2) x all 8 row-panels.
    const int b   = blockIdx.x + blockIdx.y * 24;  // 0..191
    const int xcd = b & 7;
    const int idx = b >> 3;                        // 0..23
    const int bx  = xcd * 3 + (idx >> 3);          // 0..23 col-panel
    const int by  = idx & 7;                       // 0..7  row-panel
    const int which = bx >> 3;                     // 0=Q 1=K 2=V
    const int bn  = (bx & 7) * QBN;
    const int bm  = by * QBM;
    const ushort* Ap = Astack + (size_t)which * 4194304;
    const ushort* Bp = Wstack + (size_t)which * 4194304;

    const int rl  = lane >> 3;                          // staging row-in-8
    const int csw = (((lane & 7) ^ ((lane >> 3) & 7)) * 8);  // pre-swizzled col
    const int lm  = lane & 15;
    const int lg  = lane >> 4;
    const char* ldsb = reinterpret_cast<const char*>(lds);

    auto ldA = [&](int slot, int m, int kk) -> short8v {
        const int row = m * 16 + lm;
        const int off = (slot * 16384 + (wid >> 2) * 8192) * 2 + row * 128
                      + (((kk * 4 + lg) ^ (row & 7)) * 16);
        return *reinterpret_cast<const short8v*>(ldsb + off);
    };
    auto ldB = [&](int slot, int n, int kk) -> short8v {
        const int row = (wid & 1) * 64 + n * 16 + lm;
        const int off = (32768 + slot * 16384 + ((wid & 3) >> 1) * 8192) * 2
                      + row * 128 + (((kk * 4 + lg) ^ (row & 7)) * 16);
        return *reinterpret_cast<const short8v*>(ldsb + off);
    };

    floatx4 acc[8][4] = {};
    short8v bf[4][2];
    short8v af[2][2];

    // prologue: A(0), B(0), B(1) = 6 half-tiles (12 loads/wave);
    // vmcnt(4) -> A(0),B(0) landed, B(1) (4 loads) still in flight.
    STAGE_A(0, 0); STAGE_A(0, 1);
    STAGE_B(0, 0); STAGE_B(0, 1);
    STAGE_B(1, 0); STAGE_B(1, 1);
    VMW4();
    BARRIER();

    for (int i = 0; i < 16; ++i) {
        const int t = 2 * i;
        PH(0, 0, (void)0, STAGE_A(t + 1, 0));
        PH(0, 1, (void)0, STAGE_A(t + 1, 1));
        PH(0, 2, (void)0, STAGE_B(t + 2, 0));
        PH(0, 3, VMW4(),  STAGE_B(t + 2, 1));
        PH(1, 0, (void)0, STAGE_A(t + 2, 0));
        PH(1, 1, (void)0, STAGE_A(t + 2, 1));
        PH(1, 2, (void)0, STAGE_B(t + 3, 0));
        PH(1, 3, VMW4(),  STAGE_B(t + 3, 1));
    }
    asm volatile("s_waitcnt vmcnt(0)" ::: "memory");

    // ---- epilogue (which-uniform): rotary->bQ / rotary->bK / transpose->bVt
    const float* bias = which == 0 ? bq : which == 1 ? bk : bv;
    #pragma unroll
    for (int m = 0; m < 8; ++m) {
        #pragma unroll
        for (int n = 0; n < 4; ++n) {
            const int col = bn + (wid & 3) * 64 + n * 16 + lm;
            const float bz = bias[col];
            const int row0 = bm + (wid >> 2) * 128 + m * 16 + lg * 4;
            if (which == 2) {
                ushort o4[4];
                #pragma unroll
                for (int j = 0; j < 4; ++j)
                    o4[j] = f2bf(acc[m][n][j] + bz);
                *reinterpret_cast<uint2*>(&outVt[(size_t)col * T_LEN + row0]) =
                    *reinterpret_cast<const uint2*>(o4);
            } else {
                ushort* O = which == 0 ? outQ : outK;
                const int p = (col & 63) >> 1;
                const bool even = (col & 1) == 0;
                #pragma unroll
                for (int j = 0; j < 4; ++j) {
                    const int row = row0 + j;
                    const float v = acc[m][n][j] + bz;
                    const float pv = __shfl_xor(v, 1);
                    const float s  = sinp[row * HALF + p];
                    const float c  = cosp[row * HALF + p];
                    const float xs = xscale[row * HALF + p];
                    float scale;
                    if (which == 0) {
                        float sa = 1.f;
                        if (row >= 2) {
                            const float lv = __logf((float)row) * 0.14426950408889634f;
                            sa = lv > 1.f ? lv : 1.f;
                        }
                        scale = xs * sa * 0.125f;   // * HD^-0.5
                    } else {
                        scale = 1.0f / xs;
                    }
                    const float C_ = c * scale, S_ = s * scale;
                    const float outv = even ? v * C_ - pv * S_ : v * C_ + pv * S_;
                    O[(size_t)row * EMB + col] = f2bf(outv);
                }
            }
        }
    }
}

// ---------------------------------------------------------------------------
// Output projection GEMM (m97 structure, fp32 out): C = A * B^T + bias
// ---------------------------------------------------------------------------
#define GBM 128
#define GBN 128
#define GBK 64

__global__ __launch_bounds__(256) void gemm_out(
    const ushort* __restrict__ A,
    const ushort* __restrict__ B,
    const float* __restrict__ bias,
    float* __restrict__ C)
{
    __shared__ ushort As[GBM * GBK];
    __shared__ ushort Bs[GBN * GBK];
    const int tid  = threadIdx.x;
    const int lane = tid & 63;
    const int wid  = tid >> 6;
    const int bm = blockIdx.y * GBM;
    const int bn = blockIdx.x * GBN;
    const int wr = (wid >> 1) * 64;
    const int wc = (wid & 1) * 64;

    floatx4 acc[4][4] = {};

    const int lrow  = lane >> 3;
    const int lcolb = (lane & 7) * 8;

    for (int k0 = 0; k0 < EMB; k0 += GBK) {
        #pragma unroll
        for (int c = 0; c < 4; ++c) {
            const int chunk = wid * 4 + c;
            const int row = chunk * 8 + lrow;
            gload_lds16(&A[(size_t)(bm + row) * EMB + k0 + lcolb], &As[chunk * 512]);
            gload_lds16(&B[(size_t)(bn + row) * EMB + k0 + lcolb], &Bs[chunk * 512]);
        }
        __syncthreads();
        #pragma unroll
        for (int kk = 0; kk < 2; ++kk) {
            short8v a[4], b[4];
            #pragma unroll
            for (int m = 0; m < 4; ++m)
                a[m] = *reinterpret_cast<const short8v*>(
                    &As[(wr + m * 16 + (lane & 15)) * GBK + kk * 32 + (lane >> 4) * 8]);
            #pragma unroll
            for (int n = 0; n < 4; ++n)
                b[n] = *reinterpret_cast<const short8v*>(
                    &Bs[(wc + n * 16 + (lane & 15)) * GBK + kk * 32 + (lane >> 4) * 8]);
            #pragma unroll
            for (int m = 0; m < 4; ++m)
                #pragma unroll
                for (int n = 0; n < 4; ++n)
                    acc[m][n] = __builtin_amdgcn_mfma_f32_16x16x32_bf16(
                        a[m], b[n], acc[m][n], 0, 0, 0);
        }
        __syncthreads();
    }

    const int cr = (lane >> 4) * 4;
    const int cc = lane & 15;
    #pragma unroll
    for (int m = 0; m < 4; ++m) {
        #pragma unroll
        for (int n = 0; n < 4; ++n) {
            const int col = bn + wc + n * 16 + cc;
            const float bz = bias[col];
            #pragma unroll
            for (int j = 0; j < 4; ++j) {
                const int row = bm + wr + m * 16 + cr + j;
                C[(size_t)row * EMB + col] = acc[m][n][j] + bz;
            }
        }
    }
}

// ---------------------------------------------------------------------------
// MFMA flash attention (bf16, causal, online softmax), 2-phase pipelined,
// defer-max, cvt_pk P-packing, LPT block order. (unchanged from round 5)
// ---------------------------------------------------------------------------
__global__ __launch_bounds__(256) void flash_attn_mfma(
    const ushort* __restrict__ Qb,   // [T][EMB] bf16 (rotary+scaled)
    const ushort* __restrict__ Kb,   // [T][EMB] bf16 (rotary)
    const ushort* __restrict__ Vt,   // [EMB][T] bf16 (per-head [d][t])
    ushort* __restrict__ Ob)         // [T][EMB] bf16
{
    __shared__ ushort Ks[2][64 * 64];
    __shared__ ushort Vs[2][64 * 64];
    __shared__ ushort Ps[4][16 * 64];

    const int h   = blockIdx.x;
    const int qb  = (T_LEN / 64 - 1) - blockIdx.y;   // LPT: heavy blocks first
    const int tid = threadIdx.x;
    const int lane = tid & 63;
    const int wid  = tid >> 6;
    const int qrow_w = qb * 64 + wid * 16;
    const int lm = lane & 15;
    const int lg = lane >> 4;

    short8v qf[2];
    {
        const ushort* qp = &Qb[(size_t)(qrow_w + lm) * EMB + h * HD + lg * 8];
        qf[0] = *reinterpret_cast<const short8v*>(qp);
        qf[1] = *reinterpret_cast<const short8v*>(qp + 32);
    }

    floatx4 oacc[4] = {};
    float m = -1e30f, l = 0.f;

    const int srow = lane >> 3;
    const int schk = lane & 7;

    {
        #pragma unroll
        for (int i = 0; i < 2; ++i) {
            const int slot = wid * 2 + i;
            const int row  = slot * 8 + srow;
            const int cswz = (schk ^ (row & 7)) * 8;
            gload_lds16(&Kb[(size_t)row * EMB + h * HD + cswz], &Ks[0][slot * 512]);
            gload_lds16(&Vt[(size_t)(h * HD + row) * T_LEN + cswz], &Vs[0][slot * 512]);
        }
    }
    __syncthreads();

    for (int kb = 0; kb <= qb; ++kb) {
        const int cur = kb & 1;
        if (kb < qb) {
            const int nkb = kb + 1;
            #pragma unroll
            for (int i = 0; i < 2; ++i) {
                const int slot = wid * 2 + i;
                const int row  = slot * 8 + srow;
                const int cswz = (schk ^ (row & 7)) * 8;
                gload_lds16(&Kb[(size_t)(nkb * 64 + row) * EMB + h * HD + cswz],
                            &Ks[cur ^ 1][slot * 512]);
                gload_lds16(&Vt[(size_t)(h * HD + row) * T_LEN + nkb * 64 + cswz],
                            &Vs[cur ^ 1][slot * 512]);
            }
        }

        float sv[16];
        #pragma unroll
        for (int t = 0; t < 4; ++t) {
            floatx4 sacc = {};
            const int srow_l = t * 16 + lm;
            const char* krow = reinterpret_cast<const char*>(Ks[cur]) + srow_l * 128;
            const int swz = (srow_l & 7) << 4;
            #pragma unroll
            for (int kk = 0; kk < 2; ++kk) {
                const int cb = (kk * 64 + lg * 16) ^ swz;
                short8v kf = *reinterpret_cast<const short8v*>(krow + cb);
                sacc = __builtin_amdgcn_mfma_f32_16x16x32_bf16(kf, qf[kk], sacc, 0, 0, 0);
            }
            sv[t * 4 + 0] = sacc[0]; sv[t * 4 + 1] = sacc[1];
            sv[t * 4 + 2] = sacc[2]; sv[t * 4 + 3] = sacc[3];
        }

        const int qg = qrow_w + lm;
        if (kb == qb) {
            #pragma unroll
            for (int t = 0; t < 4; ++t)
                #pragma unroll
                for (int r = 0; r < 4; ++r) {
                    const int sg = kb * 64 + t * 16 + lg * 4 + r;
                    if (sg > qg) sv[t * 4 + r] = -1e30f;
                }
        }

        float mx = sv[0];
        #pragma unroll
        for (int i = 1; i < 16; ++i) mx = fmaxf(mx, sv[i]);
        mx = fmaxf(mx, __shfl_xor(mx, 16));
        mx = fmaxf(mx, __shfl_xor(mx, 32));
        float corr = 1.f;
        if (!__all(mx - m <= 8.f)) {
            const float mnew = fmaxf(m, mx);
            corr = __expf(m - mnew);
            m = mnew;
            float corr4[4];
            #pragma unroll
            for (int r = 0; r < 4; ++r)
                corr4[r] = __shfl(corr, lg * 4 + r);
            #pragma unroll
            for (int td = 0; td < 4; ++td)
                #pragma unroll
                for (int r = 0; r < 4; ++r)
                    oacc[td][r] *= corr4[r];
        }
        float ps = 0.f;
        unsigned pw[8];
        #pragma unroll
        for (int i = 0; i < 8; ++i) {
            const float p0 = __expf(sv[2 * i + 0] - m);
            const float p1 = __expf(sv[2 * i + 1] - m);
            ps += p0 + p1;
            const __hip_bfloat162 h2 = __float22bfloat162_rn(make_float2(p0, p1));
            pw[i] = *reinterpret_cast<const unsigned*>(&h2);
        }
        ps += __shfl_xor(ps, 16);
        ps += __shfl_xor(ps, 32);
        l = l * corr + ps;

        {
            char* pbase = reinterpret_cast<char*>(&Ps[wid][0]) + lm * 128;
            const int swz = (lm & 7) << 4;
            #pragma unroll
            for (int t = 0; t < 4; ++t) {
                uint2 w;
                w.x = pw[2 * t + 0];
                w.y = pw[2 * t + 1];
                const int cb = (t * 32 + lg * 8) ^ swz;
                *reinterpret_cast<uint2*>(pbase + cb) = w;
            }
        }

        const char* pwave = reinterpret_cast<const char*>(&Ps[wid][0]);
        #pragma unroll
        for (int kk = 0; kk < 2; ++kk) {
            const int acb = (kk * 64 + lg * 16) ^ ((lm & 7) << 4);
            short8v pa = *reinterpret_cast<const short8v*>(pwave + lm * 128 + acb);
            #pragma unroll
            for (int td = 0; td < 4; ++td) {
                const int d = td * 16 + lm;
                const int bcb = (kk * 64 + lg * 16) ^ ((d & 7) << 4);
                short8v vb = *reinterpret_cast<const short8v*>(
                    reinterpret_cast<const char*>(Vs[cur]) + d * 128 + bcb);
                oacc[td] = __builtin_amdgcn_mfma_f32_16x16x32_bf16(pa, vb, oacc[td], 0, 0, 0);
            }
        }

        __syncthreads();
    }

    float invl[4];
    #pragma unroll
    for (int r = 0; r < 4; ++r)
        invl[r] = 1.f / __shfl(l, lg * 4 + r);
    #pragma unroll
    for (int td = 0; td < 4; ++td) {
        #pragma unroll
        for (int r = 0; r < 4; ++r) {
            const int trow = qrow_w + lg * 4 + r;
            const int col  = h * HD + td * 16 + lm;
            Ob[(size_t)trow * EMB + col] = f2bf(oacc[td][r] * invl[r]);
        }
    }
}

// ---------------------------------------------------------------------------
// Launch. 4 dispatches. Workspace (88 MB), all bf16:
//   +0  [Wq|Wk|Wv] (24MB stacked)  +24 bWo
//   +32 [bAq|bAk|bAv] (24MB stacked)
//   +56 bQ   +64 bK   +72 bVt  +80 bAo
// ---------------------------------------------------------------------------
extern "C" void kernel_launch(void* const* d_in, const int* in_sizes, int n_in,
                              void* d_out, int out_size, void* d_ws, size_t ws_size,
                              hipStream_t stream) {
    const float* query = (const float*)d_in[0];
    const float* key   = (const float*)d_in[1];
    const float* value = (const float*)d_in[2];
    const float* Wq = (const float*)d_in[3];
    const float* bq = (const float*)d_in[4];
    const float* Wk = (const float*)d_in[5];
    const float* bk = (const float*)d_in[6];
    const float* Wv = (const float*)d_in[7];
    const float* bv = (const float*)d_in[8];
    const float* Wo = (const float*)d_in[9];
    const float* bo = (const float*)d_in[10];
    const float* sinp   = (const float*)d_in[11];
    const float* cosp   = (const float*)d_in[12];
    const float* xscale = (const float*)d_in[13];
    float* out = (float*)d_out;

    const size_t MB = 1024 * 1024;
    char* ws = (char*)d_ws;
    ushort* bWqkv = (ushort*)(ws + 0 * MB);
    ushort* bWo   = (ushort*)(ws + 24 * MB);
    ushort* bAqkv = (ushort*)(ws + 32 * MB);
    ushort* bQ  = (ushort*)(ws + 56 * MB);
    ushort* bK  = (ushort*)(ws + 64 * MB);
    ushort* bVt = (ushort*)(ws + 72 * MB);
    ushort* bAo = (ushort*)(ws + 80 * MB);

    conv_all<<<7 * 524288 / 256, 256, 0, stream>>>(
        Wq, Wk, Wv, Wo, query, key, value, bWqkv);

    dim3 gQKV(24, 8);                          // 192 blocks, 512 thr
    gemm_qkv8<<<gQKV, 512, 0, stream>>>(bAqkv, bWqkv, bq, bk, bv,
                                        bQ, bK, bVt, sinp, cosp, xscale);

    dim3 gFlash(NH, T_LEN / 64);
    flash_attn_mfma<<<gFlash, 256, 0, stream>>>(bQ, bK, bVt, bAo);

    dim3 gGemm(EMB / GBN, T_LEN / GBM);
    gemm_out<<<gGemm, 256, 0, stream>>>(bAo, bWo, bo, out);
}